// Round 5
// baseline (1194.733 us; speedup 1.0000x reference)
//
#include <hip/hip_runtime.h>
#include <hip/hip_bf16.h>
#include <math.h>

typedef __hip_bfloat16 bf16;
typedef __attribute__((ext_vector_type(8))) short bf16x8;
typedef __attribute__((ext_vector_type(4))) float f32x4;

#define GPTR(p) ((__attribute__((address_space(1))) void*)(void*)(p))
#define LPTR(p) ((__attribute__((address_space(3))) void*)(void*)(p))

static constexpr int kB = 4, kL = 2048, kD = 1024, kV = 32000;
static constexpr int kM = kB * kL;                 // 8192
static constexpr int kNC = 16, kCH = kL / kNC;     // 16 chunks of 128

// ---------------- sincos tables ----------------
__global__ void k_sincos(const float* __restrict__ ph, float* __restrict__ c,
                         float* __restrict__ s, int n) {
  int i = blockIdx.x * 256 + threadIdx.x;
  if (i < n) {
    float sv, cv;
    sincosf(ph[i], &sv, &cv);
    c[i] = cv;
    s[i] = sv;
  }
}

// ---------------- transpose + f32 -> bf16 : in[R][C] -> out[C][R] ----------------
__global__ void k_tcvt64(const float* __restrict__ in, bf16* __restrict__ out,
                         int R, int C) {
  __shared__ bf16 tile[64][66];
  int c0 = blockIdx.x * 64, r0 = blockIdx.y * 64;
  int tid = threadIdx.x;  // 256
  int cq = tid & 15;
  int rr = tid >> 4;
#pragma unroll
  for (int i = 0; i < 4; i++) {
    int r = rr + i * 16;
    float4 v = *(const float4*)(in + (size_t)(r0 + r) * C + c0 + cq * 4);
    tile[r][cq * 4 + 0] = __float2bfloat16(v.x);
    tile[r][cq * 4 + 1] = __float2bfloat16(v.y);
    tile[r][cq * 4 + 2] = __float2bfloat16(v.z);
    tile[r][cq * 4 + 3] = __float2bfloat16(v.w);
  }
  __syncthreads();
  int rb = tid & 7;
  int cc = tid >> 3;
#pragma unroll
  for (int i = 0; i < 2; i++) {
    int c = cc + i * 32;
    bf16x8 p;
#pragma unroll
    for (int j = 0; j < 8; j++) p[j] = *(const short*)&tile[rb * 8 + j][c];
    *(bf16x8*)(out + (size_t)(c0 + c) * R + r0 + rb * 8) = p;
  }
}

// ---------------- fused embedding gather + layernorm (row = blockIdx) ----------
__global__ void k_embln(const int* __restrict__ tok, const float* __restrict__ emb,
                        const float* __restrict__ g, const float* __restrict__ b,
                        float* __restrict__ h, bf16* __restrict__ ob,
                        float* __restrict__ of) {
  int row = blockIdx.x;
  int tid = threadIdx.x;
  int t = tok[row];
  float4 v = ((const float4*)(emb + (size_t)t * kD))[tid];
  ((float4*)(h + (size_t)row * kD))[tid] = v;  // raw embed (residual source)
  float sum = v.x + v.y + v.z + v.w;
  float sq = fmaf(v.x, v.x, fmaf(v.y, v.y, fmaf(v.z, v.z, v.w * v.w)));
#pragma unroll
  for (int o = 32; o > 0; o >>= 1) {
    sum += __shfl_down(sum, o);
    sq += __shfl_down(sq, o);
  }
  __shared__ float ss[4], sk[4];
  int w = tid >> 6;
  if ((tid & 63) == 0) { ss[w] = sum; sk[w] = sq; }
  __syncthreads();
  float ts = ss[0] + ss[1] + ss[2] + ss[3];
  float tq = sk[0] + sk[1] + sk[2] + sk[3];
  float mu = ts * (1.0f / kD);
  float var = tq * (1.0f / kD) - mu * mu;
  float rstd = rsqrtf(var + 1e-5f);
  float4 gg = ((const float4*)g)[tid];
  float4 bb = ((const float4*)b)[tid];
  float4 o;
  o.x = fmaf((v.x - mu) * rstd, gg.x, bb.x);
  o.y = fmaf((v.y - mu) * rstd, gg.y, bb.y);
  o.z = fmaf((v.z - mu) * rstd, gg.z, bb.z);
  o.w = fmaf((v.w - mu) * rstd, gg.w, bb.w);
  union { ushort4 u; bf16 hh[4]; } pk;
  pk.hh[0] = __float2bfloat16(o.x);
  pk.hh[1] = __float2bfloat16(o.y);
  pk.hh[2] = __float2bfloat16(o.z);
  pk.hh[3] = __float2bfloat16(o.w);
  *(ushort4*)(ob + (size_t)row * kD + tid * 4) = pk.u;
  ((float4*)(of + (size_t)row * kD))[tid] = o;
}

// ---------------- row layernorm (D=1024), 256 threads/row ----------------
template <bool WF32>
__global__ void k_ln(const float* __restrict__ in, const float* __restrict__ g,
                     const float* __restrict__ b, bf16* __restrict__ ob,
                     float* __restrict__ of) {
  int row = blockIdx.x;
  int tid = threadIdx.x;
  const float4* x4 = (const float4*)(in + (size_t)row * kD);
  float4 v = x4[tid];
  float sum = v.x + v.y + v.z + v.w;
  float sq = fmaf(v.x, v.x, fmaf(v.y, v.y, fmaf(v.z, v.z, v.w * v.w)));
#pragma unroll
  for (int o = 32; o > 0; o >>= 1) {
    sum += __shfl_down(sum, o);
    sq += __shfl_down(sq, o);
  }
  __shared__ float ss[4], sk[4];
  int w = tid >> 6;
  if ((tid & 63) == 0) { ss[w] = sum; sk[w] = sq; }
  __syncthreads();
  float ts = ss[0] + ss[1] + ss[2] + ss[3];
  float tq = sk[0] + sk[1] + sk[2] + sk[3];
  float mu = ts * (1.0f / kD);
  float var = tq * (1.0f / kD) - mu * mu;
  float rstd = rsqrtf(var + 1e-5f);
  float4 gg = ((const float4*)g)[tid];
  float4 bb = ((const float4*)b)[tid];
  float4 o;
  o.x = fmaf((v.x - mu) * rstd, gg.x, bb.x);
  o.y = fmaf((v.y - mu) * rstd, gg.y, bb.y);
  o.z = fmaf((v.z - mu) * rstd, gg.z, bb.z);
  o.w = fmaf((v.w - mu) * rstd, gg.w, bb.w);
  union { ushort4 u; bf16 h[4]; } pk;
  pk.h[0] = __float2bfloat16(o.x);
  pk.h[1] = __float2bfloat16(o.y);
  pk.h[2] = __float2bfloat16(o.z);
  pk.h[3] = __float2bfloat16(o.w);
  *(ushort4*)(ob + (size_t)row * kD + tid * 4) = pk.u;
  if constexpr (WF32) {
    ((float4*)(of + (size_t)row * kD))[tid] = o;
  }
}

// ---------------- phasor scan: pass A (chunk partial sums) ----------------
__global__ void k_scan_part(const float* __restrict__ v, const float* __restrict__ c,
                            const float* __restrict__ s, float* __restrict__ pr,
                            float* __restrict__ pi) {
  int tid = blockIdx.x * 256 + threadIdx.x;  // b*16384 + ch*1024 + d
  int d = tid & (kD - 1);
  int ch = (tid >> 10) & (kNC - 1);
  int b = tid >> 14;
  const float* vp = v + ((size_t)b * kL + ch * kCH) * kD + d;
  const float* cp = c + (size_t)(ch * kCH) * kD + d;
  const float* sp = s + (size_t)(ch * kCH) * kD + d;
  float ar = 0.f, ai = 0.f;
  for (int i = 0; i < kCH; i++) {
    float vv = vp[i * kD];
    ar = fmaf(vv, cp[i * kD], ar);
    ai = fmaf(vv, sp[i * kD], ai);
  }
  pr[tid] = ar;
  pi[tid] = ai;
}

// ---------------- phasor scan: pass B (apply, in-place over v) ----------------
__global__ void k_scan_apply(float* __restrict__ v, const float* __restrict__ c,
                             const float* __restrict__ s, const float* __restrict__ pr,
                             const float* __restrict__ pi) {
  int tid = blockIdx.x * 256 + threadIdx.x;
  int d = tid & (kD - 1);
  int ch = (tid >> 10) & (kNC - 1);
  int b = tid >> 14;
  float ar = 0.f, ai = 0.f;
  int pbase = (b << 14) + d;
  for (int cc = 0; cc < ch; cc++) {
    ar += pr[pbase + cc * kD];
    ai += pi[pbase + cc * kD];
  }
  float* vp = v + ((size_t)b * kL + ch * kCH) * kD + d;
  const float* cp = c + (size_t)(ch * kCH) * kD + d;
  const float* sp = s + (size_t)(ch * kCH) * kD + d;
  for (int i = 0; i < kCH; i++) {
    float vv = vp[i * kD];
    float cv = cp[i * kD], sv = sp[i * kD];
    ar = fmaf(vv, cv, ar);
    ai = fmaf(vv, sv, ai);
    vp[i * kD] = (ar * cv + ai * sv) * 0.03125f;  // 1/sqrt(1024)
  }
}

// ---------------- 128x128-tile GEMM (R0 config, proven) for small D x D ----
template <int MODE>
__global__ __launch_bounds__(256) void k_gemm_bt(
    const bf16* __restrict__ A, const bf16* __restrict__ BT,
    const float* __restrict__ bias, const float* __restrict__ xres,
    const float* __restrict__ hres, float* __restrict__ Cout,
    int Md, int Nd, int Kd) {
  __shared__ __align__(16) bf16 As[128 * 32];
  __shared__ __align__(16) bf16 Bs[128 * 32];
  int nwg = gridDim.x * gridDim.y;
  int wg = blockIdx.y * gridDim.x + blockIdx.x;
  int per = nwg >> 3;
  int sw = (wg & 7) * per + (wg >> 3);
  int bm = sw % gridDim.x;
  int bn = sw / gridDim.x;
  int m0 = bm * 128, n0 = bn * 128;
  int tid = threadIdx.x;
  int wid = tid >> 6, lane = tid & 63;
  int wr = wid >> 1, wc = wid & 1;

  f32x4 acc[4][4];
#pragma unroll
  for (int i = 0; i < 4; i++)
#pragma unroll
    for (int j = 0; j < 4; j++) acc[i][j] = (f32x4){0.f, 0.f, 0.f, 0.f};

  const bf16* Abase = A + (size_t)m0 * Kd;
  const bf16* Bbase = BT + (size_t)n0 * Kd;
  int lr = lane >> 2;
  int lk = (lane & 3) * 8;
  int frow = lane & 15;
  int fk = (lane >> 4) * 8;

  for (int k0 = 0; k0 < Kd; k0 += 32) {
#pragma unroll
    for (int c = 0; c < 2; c++) {
      int ch = wid + c * 4;
      __builtin_amdgcn_global_load_lds(GPTR(Abase + (size_t)(ch * 16 + lr) * Kd + k0 + lk),
                                       LPTR(As + ch * 512), 16, 0, 0);
      __builtin_amdgcn_global_load_lds(GPTR(Bbase + (size_t)(ch * 16 + lr) * Kd + k0 + lk),
                                       LPTR(Bs + ch * 512), 16, 0, 0);
    }
    asm volatile("s_waitcnt vmcnt(0)" ::: "memory");
    __syncthreads();
    bf16x8 af[4], bfr[4];
#pragma unroll
    for (int i = 0; i < 4; i++) {
      af[i] = *(const bf16x8*)(As + (wr * 64 + i * 16 + frow) * 32 + fk);
      bfr[i] = *(const bf16x8*)(Bs + (wc * 64 + i * 16 + frow) * 32 + fk);
    }
#pragma unroll
    for (int i = 0; i < 4; i++)
#pragma unroll
      for (int j = 0; j < 4; j++)
        acc[i][j] = __builtin_amdgcn_mfma_f32_16x16x32_bf16(af[i], bfr[j], acc[i][j], 0, 0, 0);
    __syncthreads();
  }

  int cr = (lane >> 4) * 4;
  int ccl = lane & 15;
#pragma unroll
  for (int i = 0; i < 4; i++) {
#pragma unroll
    for (int j = 0; j < 4; j++) {
      int col = n0 + wc * 64 + j * 16 + ccl;
      float bv = bias[col];
#pragma unroll
      for (int r = 0; r < 4; r++) {
        int row = m0 + wr * 64 + i * 16 + cr + r;
        size_t idx = (size_t)row * Nd + col;
        float val = acc[i][j][r] + bv;
        if (MODE == 1) val += hres[idx] + xres[idx];
        Cout[idx] = val;
      }
    }
  }
}

// ============================================================================
// PERSISTENT 256x256 head GEMM (R5). Inner 4-phase K-loop is byte-identical
// to the proven R0 schedule (vmcnt(6) counted gates, dbuf A/B, swizzled LDS,
// setprio). Change: grid = 256 blocks (1/CU); each block owns a FIXED bm
// (A panel L2-pinned) and walks bn across 15-16 segments via the R0 XCD
// swizzle applied to virtual tile id v = seg*256 + p:
//   base = 500*(p&7) + (p>>3);  bm = base%32 (const);  bn = base/32 + seg.
// Cross-segment staging: t+2 >= NT targets next segment's B stripe
// (bSeg + 256*K) and the same A panel ((u&15)*64). Eliminates 15 per-round
// prologue fills; epilogue stores overlap the next segment's first K-tile
// (drain at the next vmcnt(6) gate instead of vmcnt(0)+endpgm).
// Rounds 0-4 showed dur is insensitive to HBM traffic and latency slack;
// the per-block fixed overhead at NT=16 is the remaining structural cost.
// ============================================================================
__global__ __launch_bounds__(512, 2) void k_gemmhead(
    const bf16* __restrict__ A, const bf16* __restrict__ BT,
    const float* __restrict__ bias, float* __restrict__ Cout) {
  __shared__ __align__(16) bf16 As[2][16384];  // [buf][256 rows x 64 k]
  __shared__ __align__(16) bf16 Bs[2][16384];

  constexpr int Kd = kD;              // 1024
  constexpr int Nd = kV;              // 32000
  constexpr int NT = Kd >> 6;         // 16 K-tiles of 64
  constexpr int TM = kM / 256;        // 32 bm values
  constexpr int TT = TM * (kV / 256); // 4000 tiles
  constexpr int P = 256;              // persistent blocks
  constexpr int PER = TT / 8;         // 500

  int p = blockIdx.x;
  int base = PER * (p & 7) + (p >> 3);
  int bm = base & (TM - 1);           // constant per block
  int bn0 = base >> 5;                // + seg per segment
  int nseg = (TT - p + P - 1) / P;    // 16 for p<160, else 15
  int m0 = bm * 256;

  int tid = threadIdx.x;
  int wid = tid >> 6, lane = tid & 63;
  int wr = wid >> 2, wc = wid & 3;

  size_t KdS = (size_t)Kd;
  int srow = tid >> 3;
  int sk = (((tid & 7) ^ (srow & 7)) << 3);
  const bf16* aSrc = A + (size_t)(m0 + srow) * KdS + sk;
  const bf16* bSeg = BT + ((size_t)bn0 * 256 + srow) * KdS + sk;
  int ldst = wid * 512;

#define STAGE_A(buf, h, u)                                                                   \
  do {                                                                                       \
    int kk = ((u) & (NT - 1)) * 64;                                                          \
    __builtin_amdgcn_global_load_lds(GPTR(aSrc + (size_t)((h) * 128) * KdS + kk),            \
                                     LPTR(&As[buf][(h) * 8192 + ldst]), 16, 0, 0);           \
    __builtin_amdgcn_global_load_lds(GPTR(aSrc + (size_t)((h) * 128 + 64) * KdS + kk),       \
                                     LPTR(&As[buf][(h) * 8192 + 4096 + ldst]), 16, 0, 0);    \
  } while (0)
#define STAGE_B(buf, h, u)                                                                   \
  do {                                                                                       \
    const bf16* bp = bSeg + ((u) >= NT ? (size_t)256 * KdS : (size_t)0);                     \
    int kk = ((u) & (NT - 1)) * 64;                                                          \
    __builtin_amdgcn_global_load_lds(GPTR(bp + (size_t)((h) * 128) * KdS + kk),              \
                                     LPTR(&Bs[buf][(h) * 8192 + ldst]), 16, 0, 0);           \
    __builtin_amdgcn_global_load_lds(GPTR(bp + (size_t)((h) * 128 + 64) * KdS + kk),         \
                                     LPTR(&Bs[buf][(h) * 8192 + 4096 + ldst]), 16, 0, 0);    \
  } while (0)

  int frow = lane & 15;
  int khi = lane >> 4;
  int rx = frow & 7;
  int lk0 = ((khi) ^ rx) << 3;
  int lk1 = ((4 + khi) ^ rx) << 3;
  int wr16 = wr * 16, wc16 = wc * 16;

  f32x4 acc[8][4];

  // ---- prologue (segment 0): tile0 fully -> buf0, tile1 A0,B0,B1 -> buf1
  STAGE_A(0, 0, 0);
  STAGE_B(0, 0, 0);
  STAGE_B(0, 1, 0);
  STAGE_A(0, 1, 0);
  STAGE_A(1, 0, 1);
  STAGE_B(1, 0, 1);
  STAGE_B(1, 1, 1);
  asm volatile("s_waitcnt vmcnt(6)" ::: "memory");  // tile0's 8 loads landed
  __builtin_amdgcn_s_barrier();
  __builtin_amdgcn_sched_barrier(0);

  for (int seg = 0; seg < nseg; ++seg) {
    bool more = (seg + 1 < nseg);
#pragma unroll
    for (int m = 0; m < 8; m++)
#pragma unroll
      for (int n = 0; n < 4; n++) acc[m][n] = (f32x4){0.f, 0.f, 0.f, 0.f};

    for (int t = 0; t < NT; ++t) {
      int c = t & 1, o = c ^ 1;
      const bf16* Ac = As[c];
      const bf16* Bc = Bs[c];
      bf16x8 a[4][2], b[2][2], b2[2][2];

      // ===== phase 0: read a(m0..3) + b(n0..1); stage A-h1(t+1)->oth; MFMA
#pragma unroll
      for (int m = 0; m < 4; m++) {
        int ro = (m * 32 + wr16 + frow) * 64;
        a[m][0] = *(const bf16x8*)(Ac + ro + lk0);
        a[m][1] = *(const bf16x8*)(Ac + ro + lk1);
      }
#pragma unroll
      for (int n = 0; n < 2; n++) {
        int ro = (n * 64 + wc16 + frow) * 64;
        b[n][0] = *(const bf16x8*)(Bc + ro + lk0);
        b[n][1] = *(const bf16x8*)(Bc + ro + lk1);
      }
      if (t + 1 < NT || more) STAGE_A(o, 1, t + 1);
      __builtin_amdgcn_s_barrier();
      asm volatile("s_waitcnt lgkmcnt(0)" ::: "memory");
      __builtin_amdgcn_sched_barrier(0);
      __builtin_amdgcn_s_setprio(1);
#pragma unroll
      for (int m = 0; m < 4; m++)
#pragma unroll
        for (int n = 0; n < 2; n++) {
          acc[m][n] = __builtin_amdgcn_mfma_f32_16x16x32_bf16(a[m][0], b[n][0], acc[m][n], 0, 0, 0);
          acc[m][n] = __builtin_amdgcn_mfma_f32_16x16x32_bf16(a[m][1], b[n][1], acc[m][n], 0, 0, 0);
        }
      __builtin_amdgcn_s_setprio(0);
      __builtin_amdgcn_s_barrier();
      __builtin_amdgcn_sched_barrier(0);

      // ===== phase 1: read b2(n2..3); stage A-h0(t+2)->cur; MFMA
#pragma unroll
      for (int n = 0; n < 2; n++) {
        int ro = ((n + 2) * 64 + wc16 + frow) * 64;
        b2[n][0] = *(const bf16x8*)(Bc + ro + lk0);
        b2[n][1] = *(const bf16x8*)(Bc + ro + lk1);
      }
      if (t + 2 < NT || more) STAGE_A(c, 0, t + 2);
      __builtin_amdgcn_s_barrier();
      asm volatile("s_waitcnt lgkmcnt(0)" ::: "memory");
      __builtin_amdgcn_sched_barrier(0);
      __builtin_amdgcn_s_setprio(1);
#pragma unroll
      for (int m = 0; m < 4; m++)
#pragma unroll
        for (int n = 0; n < 2; n++) {
          acc[m][n + 2] = __builtin_amdgcn_mfma_f32_16x16x32_bf16(a[m][0], b2[n][0], acc[m][n + 2], 0, 0, 0);
          acc[m][n + 2] = __builtin_amdgcn_mfma_f32_16x16x32_bf16(a[m][1], b2[n][1], acc[m][n + 2], 0, 0, 0);
        }
      __builtin_amdgcn_s_setprio(0);
      __builtin_amdgcn_s_barrier();
      __builtin_amdgcn_sched_barrier(0);

      // ===== phase 2: read a(m4..7); stage B-h0(t+2)->cur; MFMA
#pragma unroll
      for (int m = 0; m < 4; m++) {
        int ro = ((m + 4) * 32 + wr16 + frow) * 64;
        a[m][0] = *(const bf16x8*)(Ac + ro + lk0);
        a[m][1] = *(const bf16x8*)(Ac + ro + lk1);
      }
      if (t + 2 < NT || more) STAGE_B(c, 0, t + 2);
      __builtin_amdgcn_s_barrier();
      asm volatile("s_waitcnt lgkmcnt(0)" ::: "memory");
      __builtin_amdgcn_sched_barrier(0);
      __builtin_amdgcn_s_setprio(1);
#pragma unroll
      for (int m = 0; m < 4; m++)
#pragma unroll
        for (int n = 0; n < 2; n++) {
          acc[m + 4][n] = __builtin_amdgcn_mfma_f32_16x16x32_bf16(a[m][0], b[n][0], acc[m + 4][n], 0, 0, 0);
          acc[m + 4][n] = __builtin_amdgcn_mfma_f32_16x16x32_bf16(a[m][1], b[n][1], acc[m + 4][n], 0, 0, 0);
        }
      __builtin_amdgcn_s_setprio(0);
      __builtin_amdgcn_s_barrier();
      __builtin_amdgcn_sched_barrier(0);

      // ===== phase 3: no reads; stage B-h1(t+2)->cur; MFMA; gate
      if (t + 2 < NT || more) STAGE_B(c, 1, t + 2);
      __builtin_amdgcn_s_barrier();
      __builtin_amdgcn_sched_barrier(0);
      __builtin_amdgcn_s_setprio(1);
#pragma unroll
      for (int m = 0; m < 4; m++)
#pragma unroll
        for (int n = 0; n < 2; n++) {
          acc[m + 4][n + 2] = __builtin_amdgcn_mfma_f32_16x16x32_bf16(a[m][0], b2[n][0], acc[m + 4][n + 2], 0, 0, 0);
          acc[m + 4][n + 2] = __builtin_amdgcn_mfma_f32_16x16x32_bf16(a[m][1], b2[n][1], acc[m + 4][n + 2], 0, 0, 0);
        }
      __builtin_amdgcn_s_setprio(0);
      if (t < NT - 2 || more) {
        asm volatile("s_waitcnt vmcnt(6)" ::: "memory");  // 3 half-tiles in flight
      } else if (t == NT - 2) {
        asm volatile("s_waitcnt vmcnt(0)" ::: "memory");  // true tail drain
      }
      __builtin_amdgcn_s_barrier();
      __builtin_amdgcn_sched_barrier(0);
    }

    // ---- segment epilogue: store this tile; stores drain at next vmcnt gate
    int n0 = (bn0 + seg) * 256;
    int cr = (lane >> 4) * 4;
    int ccl = lane & 15;
#pragma unroll
    for (int m = 0; m < 8; m++) {
#pragma unroll
      for (int n = 0; n < 4; n++) {
        int col = n0 + n * 64 + wc16 + ccl;
        float bvv = bias[col];
#pragma unroll
        for (int r2 = 0; r2 < 4; r2++) {
          int row = m0 + m * 32 + wr16 + cr + r2;
          Cout[(size_t)row * Nd + col] = acc[m][n][r2] + bvv;
        }
      }
    }
    bSeg += (size_t)256 * KdS;  // advance to next bn stripe
  }
#undef STAGE_A
#undef STAGE_B
}

extern "C" void kernel_launch(void* const* d_in, const int* in_sizes, int n_in,
                              void* d_out, int out_size, void* d_ws, size_t ws_size,
                              hipStream_t stream) {
  const int* tokens   = (const int*)d_in[0];
  const float* embed  = (const float*)d_in[1];
  const float* ln1_g  = (const float*)d_in[2];
  const float* ln1_b  = (const float*)d_in[3];
  const float* ph1    = (const float*)d_in[4];
  const float* wv1    = (const float*)d_in[5];
  const float* bv1    = (const float*)d_in[6];
  const float* lno1_g = (const float*)d_in[7];
  const float* lno1_b = (const float*)d_in[8];
  const float* wo1    = (const float*)d_in[9];
  const float* bo1    = (const float*)d_in[10];
  const float* ln2_g  = (const float*)d_in[11];
  const float* ln2_b  = (const float*)d_in[12];
  const float* ph2    = (const float*)d_in[13];
  const float* wv2    = (const float*)d_in[14];
  const float* bv2    = (const float*)d_in[15];
  const float* lno2_g = (const float*)d_in[16];
  const float* lno2_b = (const float*)d_in[17];
  const float* wo2    = (const float*)d_in[18];
  const float* bo2    = (const float*)d_in[19];
  const float* ln3_g  = (const float*)d_in[20];
  const float* ln3_b  = (const float*)d_in[21];
  const float* w_head = (const float*)d_in[22];
  const float* b_head = (const float*)d_in[23];

  float* out = (float*)d_out;

  // ws: bf16 weights (transposed) + bf16 LN output  (~91 MB)
  char* ws = (char*)d_ws;
  bf16* whT  = (bf16*)ws;                    // [V][D]
  bf16* wv1T = whT + (size_t)kV * kD;        // [D][D] each
  bf16* wo1T = wv1T + (size_t)kD * kD;
  bf16* wv2T = wo1T + (size_t)kD * kD;
  bf16* wo2T = wv2T + (size_t)kD * kD;
  bf16* xb   = wo2T + (size_t)kD * kD;       // [M][D] bf16 (LN output, reused)

  // f32 activations live in d_out (1 GB); fully overwritten by the final GEMM
  float* h  = out;                            // [M][D]
  float* xf = h + (size_t)kM * kD;            // [M][D]
  float* vb = xf + (size_t)kM * kD;           // [M][D] v / retrieved (in-place)
  float* ct = vb + (size_t)kM * kD;           // [L][D]
  float* st = ct + (size_t)kL * kD;           // [L][D]
  float* pr = st + (size_t)kL * kD;           // [B][NC][D]
  float* pi = pr + (size_t)kB * kNC * kD;

  // weight conversion (transpose to [N][K] bf16), 64x64 vectorized tiles
  k_tcvt64<<<dim3(kD / 64, kD / 64), 256, 0, stream>>>(wv1, wv1T, kD, kD);
  k_tcvt64<<<dim3(kD / 64, kD / 64), 256, 0, stream>>>(wo1, wo1T, kD, kD);
  k_tcvt64<<<dim3(kD / 64, kD / 64), 256, 0, stream>>>(wv2, wv2T, kD, kD);
  k_tcvt64<<<dim3(kD / 64, kD / 64), 256, 0, stream>>>(wo2, wo2T, kD, kD);
  k_tcvt64<<<dim3(kV / 64, kD / 64), 256, 0, stream>>>(w_head, whT, kD, kV);

  const int scanBlocks = kB * kNC * kD / 256;  // 256

  // ---- phasor block 1 ----
  k_sincos<<<(kL * kD + 255) / 256, 256, 0, stream>>>(ph1, ct, st, kL * kD);
  k_embln<<<kM, 256, 0, stream>>>(tokens, embed, ln1_g, ln1_b, h, xb, xf);
  k_gemm_bt<0><<<dim3(kM / 128, kD / 128), 256, 0, stream>>>(xb, wv1T, bv1, nullptr, nullptr,
                                                             vb, kM, kD, kD);
  k_scan_part<<<scanBlocks, 256, 0, stream>>>(vb, ct, st, pr, pi);
  k_scan_apply<<<scanBlocks, 256, 0, stream>>>(vb, ct, st, pr, pi);
  k_ln<false><<<kM, 256, 0, stream>>>(vb, lno1_g, lno1_b, xb, nullptr);
  k_gemm_bt<1><<<dim3(kM / 128, kD / 128), 256, 0, stream>>>(xb, wo1T, bo1, xf, h,
                                                             h, kM, kD, kD);

  // ---- phasor block 2 ----
  k_sincos<<<(kL * kD + 255) / 256, 256, 0, stream>>>(ph2, ct, st, kL * kD);
  k_ln<true><<<kM, 256, 0, stream>>>(h, ln2_g, ln2_b, xb, xf);
  k_gemm_bt<0><<<dim3(kM / 128, kD / 128), 256, 0, stream>>>(xb, wv2T, bv2, nullptr, nullptr,
                                                             vb, kM, kD, kD);
  k_scan_part<<<scanBlocks, 256, 0, stream>>>(vb, ct, st, pr, pi);
  k_scan_apply<<<scanBlocks, 256, 0, stream>>>(vb, ct, st, pr, pi);
  k_ln<false><<<kM, 256, 0, stream>>>(vb, lno2_g, lno2_b, xb, nullptr);
  k_gemm_bt<1><<<dim3(kM / 128, kD / 128), 256, 0, stream>>>(xb, wo2T, bo2, xf, h,
                                                             h, kM, kD, kD);

  // ---- final LN + persistent head GEMM (256 blocks, fixed-bm bn-walk) ----
  k_ln<false><<<kM, 256, 0, stream>>>(h, ln3_g, ln3_b, xb, nullptr);
  k_gemmhead<<<256, 512, 0, stream>>>(xb, whT, b_head, out);
}

// Round 6
// 1054.924 us; speedup vs baseline: 1.1325x; 1.1325x over previous
//
#include <hip/hip_runtime.h>
#include <hip/hip_bf16.h>
#include <math.h>

typedef __hip_bfloat16 bf16;
typedef __attribute__((ext_vector_type(8))) short bf16x8;
typedef __attribute__((ext_vector_type(4))) float f32x4;

#define GPTR(p) ((__attribute__((address_space(1))) void*)(void*)(p))
#define LPTR(p) ((__attribute__((address_space(3))) void*)(void*)(p))

static constexpr int kB = 4, kL = 2048, kD = 1024, kV = 32000;
static constexpr int kM = kB * kL;                 // 8192
static constexpr int kNC = 16, kCH = kL / kNC;     // 16 chunks of 128

// ---------------- sincos tables ----------------
__global__ void k_sincos(const float* __restrict__ ph, float* __restrict__ c,
                         float* __restrict__ s, int n) {
  int i = blockIdx.x * 256 + threadIdx.x;
  if (i < n) {
    float sv, cv;
    sincosf(ph[i], &sv, &cv);
    c[i] = cv;
    s[i] = sv;
  }
}

// ---------------- transpose + f32 -> bf16 : in[R][C] -> out[C][R] ----------------
// 64x64 tile, 256 threads; float4 loads, bf16x8 stores. (R1-proven, ~-40us)
__global__ void k_tcvt64(const float* __restrict__ in, bf16* __restrict__ out,
                         int R, int C) {
  __shared__ bf16 tile[64][66];
  int c0 = blockIdx.x * 64, r0 = blockIdx.y * 64;
  int tid = threadIdx.x;  // 256
  int cq = tid & 15;
  int rr = tid >> 4;
#pragma unroll
  for (int i = 0; i < 4; i++) {
    int r = rr + i * 16;
    float4 v = *(const float4*)(in + (size_t)(r0 + r) * C + c0 + cq * 4);
    tile[r][cq * 4 + 0] = __float2bfloat16(v.x);
    tile[r][cq * 4 + 1] = __float2bfloat16(v.y);
    tile[r][cq * 4 + 2] = __float2bfloat16(v.z);
    tile[r][cq * 4 + 3] = __float2bfloat16(v.w);
  }
  __syncthreads();
  int rb = tid & 7;
  int cc = tid >> 3;
#pragma unroll
  for (int i = 0; i < 2; i++) {
    int c = cc + i * 32;
    bf16x8 p;
#pragma unroll
    for (int j = 0; j < 8; j++) p[j] = *(const short*)&tile[rb * 8 + j][c];
    *(bf16x8*)(out + (size_t)(c0 + c) * R + r0 + rb * 8) = p;
  }
}

// ---------------- fused embedding gather + layernorm (row = blockIdx) ----------
__global__ void k_embln(const int* __restrict__ tok, const float* __restrict__ emb,
                        const float* __restrict__ g, const float* __restrict__ b,
                        float* __restrict__ h, bf16* __restrict__ ob,
                        float* __restrict__ of) {
  int row = blockIdx.x;
  int tid = threadIdx.x;
  int t = tok[row];
  float4 v = ((const float4*)(emb + (size_t)t * kD))[tid];
  ((float4*)(h + (size_t)row * kD))[tid] = v;  // raw embed (residual source)
  float sum = v.x + v.y + v.z + v.w;
  float sq = fmaf(v.x, v.x, fmaf(v.y, v.y, fmaf(v.z, v.z, v.w * v.w)));
#pragma unroll
  for (int o = 32; o > 0; o >>= 1) {
    sum += __shfl_down(sum, o);
    sq += __shfl_down(sq, o);
  }
  __shared__ float ss[4], sk[4];
  int w = tid >> 6;
  if ((tid & 63) == 0) { ss[w] = sum; sk[w] = sq; }
  __syncthreads();
  float ts = ss[0] + ss[1] + ss[2] + ss[3];
  float tq = sk[0] + sk[1] + sk[2] + sk[3];
  float mu = ts * (1.0f / kD);
  float var = tq * (1.0f / kD) - mu * mu;
  float rstd = rsqrtf(var + 1e-5f);
  float4 gg = ((const float4*)g)[tid];
  float4 bb = ((const float4*)b)[tid];
  float4 o;
  o.x = fmaf((v.x - mu) * rstd, gg.x, bb.x);
  o.y = fmaf((v.y - mu) * rstd, gg.y, bb.y);
  o.z = fmaf((v.z - mu) * rstd, gg.z, bb.z);
  o.w = fmaf((v.w - mu) * rstd, gg.w, bb.w);
  union { ushort4 u; bf16 hh[4]; } pk;
  pk.hh[0] = __float2bfloat16(o.x);
  pk.hh[1] = __float2bfloat16(o.y);
  pk.hh[2] = __float2bfloat16(o.z);
  pk.hh[3] = __float2bfloat16(o.w);
  *(ushort4*)(ob + (size_t)row * kD + tid * 4) = pk.u;
  ((float4*)(of + (size_t)row * kD))[tid] = o;
}

// ---------------- row layernorm (D=1024), 256 threads/row ----------------
template <bool WF32>
__global__ void k_ln(const float* __restrict__ in, const float* __restrict__ g,
                     const float* __restrict__ b, bf16* __restrict__ ob,
                     float* __restrict__ of) {
  int row = blockIdx.x;
  int tid = threadIdx.x;
  const float4* x4 = (const float4*)(in + (size_t)row * kD);
  float4 v = x4[tid];
  float sum = v.x + v.y + v.z + v.w;
  float sq = fmaf(v.x, v.x, fmaf(v.y, v.y, fmaf(v.z, v.z, v.w * v.w)));
#pragma unroll
  for (int o = 32; o > 0; o >>= 1) {
    sum += __shfl_down(sum, o);
    sq += __shfl_down(sq, o);
  }
  __shared__ float ss[4], sk[4];
  int w = tid >> 6;
  if ((tid & 63) == 0) { ss[w] = sum; sk[w] = sq; }
  __syncthreads();
  float ts = ss[0] + ss[1] + ss[2] + ss[3];
  float tq = sk[0] + sk[1] + sk[2] + sk[3];
  float mu = ts * (1.0f / kD);
  float var = tq * (1.0f / kD) - mu * mu;
  float rstd = rsqrtf(var + 1e-5f);
  float4 gg = ((const float4*)g)[tid];
  float4 bb = ((const float4*)b)[tid];
  float4 o;
  o.x = fmaf((v.x - mu) * rstd, gg.x, bb.x);
  o.y = fmaf((v.y - mu) * rstd, gg.y, bb.y);
  o.z = fmaf((v.z - mu) * rstd, gg.z, bb.z);
  o.w = fmaf((v.w - mu) * rstd, gg.w, bb.w);
  union { ushort4 u; bf16 h[4]; } pk;
  pk.h[0] = __float2bfloat16(o.x);
  pk.h[1] = __float2bfloat16(o.y);
  pk.h[2] = __float2bfloat16(o.z);
  pk.h[3] = __float2bfloat16(o.w);
  *(ushort4*)(ob + (size_t)row * kD + tid * 4) = pk.u;
  if constexpr (WF32) {
    ((float4*)(of + (size_t)row * kD))[tid] = o;
  }
}

// ---------------- phasor scan: pass A (chunk partial sums) ----------------
__global__ void k_scan_part(const float* __restrict__ v, const float* __restrict__ c,
                            const float* __restrict__ s, float* __restrict__ pr,
                            float* __restrict__ pi) {
  int tid = blockIdx.x * 256 + threadIdx.x;  // b*16384 + ch*1024 + d
  int d = tid & (kD - 1);
  int ch = (tid >> 10) & (kNC - 1);
  int b = tid >> 14;
  const float* vp = v + ((size_t)b * kL + ch * kCH) * kD + d;
  const float* cp = c + (size_t)(ch * kCH) * kD + d;
  const float* sp = s + (size_t)(ch * kCH) * kD + d;
  float ar = 0.f, ai = 0.f;
  for (int i = 0; i < kCH; i++) {
    float vv = vp[i * kD];
    ar = fmaf(vv, cp[i * kD], ar);
    ai = fmaf(vv, sp[i * kD], ai);
  }
  pr[tid] = ar;
  pi[tid] = ai;
}

// ---------------- phasor scan: pass B (apply, in-place over v) ----------------
__global__ void k_scan_apply(float* __restrict__ v, const float* __restrict__ c,
                             const float* __restrict__ s, const float* __restrict__ pr,
                             const float* __restrict__ pi) {
  int tid = blockIdx.x * 256 + threadIdx.x;
  int d = tid & (kD - 1);
  int ch = (tid >> 10) & (kNC - 1);
  int b = tid >> 14;
  float ar = 0.f, ai = 0.f;
  int pbase = (b << 14) + d;
  for (int cc = 0; cc < ch; cc++) {
    ar += pr[pbase + cc * kD];
    ai += pi[pbase + cc * kD];
  }
  float* vp = v + ((size_t)b * kL + ch * kCH) * kD + d;
  const float* cp = c + (size_t)(ch * kCH) * kD + d;
  const float* sp = s + (size_t)(ch * kCH) * kD + d;
  for (int i = 0; i < kCH; i++) {
    float vv = vp[i * kD];
    float cv = cp[i * kD], sv = sp[i * kD];
    ar = fmaf(vv, cv, ar);
    ai = fmaf(vv, sv, ai);
    vp[i * kD] = (ar * cv + ai * sv) * 0.03125f;  // 1/sqrt(1024)
  }
}

// ---------------- 128x128-tile GEMM (R0 config, proven) for small D x D ----
template <int MODE>
__global__ __launch_bounds__(256) void k_gemm_bt(
    const bf16* __restrict__ A, const bf16* __restrict__ BT,
    const float* __restrict__ bias, const float* __restrict__ xres,
    const float* __restrict__ hres, float* __restrict__ Cout,
    int Md, int Nd, int Kd) {
  __shared__ __align__(16) bf16 As[128 * 32];
  __shared__ __align__(16) bf16 Bs[128 * 32];
  int nwg = gridDim.x * gridDim.y;
  int wg = blockIdx.y * gridDim.x + blockIdx.x;
  int per = nwg >> 3;
  int sw = (wg & 7) * per + (wg >> 3);
  int bm = sw % gridDim.x;
  int bn = sw / gridDim.x;
  int m0 = bm * 128, n0 = bn * 128;
  int tid = threadIdx.x;
  int wid = tid >> 6, lane = tid & 63;
  int wr = wid >> 1, wc = wid & 1;

  f32x4 acc[4][4];
#pragma unroll
  for (int i = 0; i < 4; i++)
#pragma unroll
    for (int j = 0; j < 4; j++) acc[i][j] = (f32x4){0.f, 0.f, 0.f, 0.f};

  const bf16* Abase = A + (size_t)m0 * Kd;
  const bf16* Bbase = BT + (size_t)n0 * Kd;
  int lr = lane >> 2;
  int lk = (lane & 3) * 8;
  int frow = lane & 15;
  int fk = (lane >> 4) * 8;

  for (int k0 = 0; k0 < Kd; k0 += 32) {
#pragma unroll
    for (int c = 0; c < 2; c++) {
      int ch = wid + c * 4;
      __builtin_amdgcn_global_load_lds(GPTR(Abase + (size_t)(ch * 16 + lr) * Kd + k0 + lk),
                                       LPTR(As + ch * 512), 16, 0, 0);
      __builtin_amdgcn_global_load_lds(GPTR(Bbase + (size_t)(ch * 16 + lr) * Kd + k0 + lk),
                                       LPTR(Bs + ch * 512), 16, 0, 0);
    }
    asm volatile("s_waitcnt vmcnt(0)" ::: "memory");
    __syncthreads();
    bf16x8 af[4], bfr[4];
#pragma unroll
    for (int i = 0; i < 4; i++) {
      af[i] = *(const bf16x8*)(As + (wr * 64 + i * 16 + frow) * 32 + fk);
      bfr[i] = *(const bf16x8*)(Bs + (wc * 64 + i * 16 + frow) * 32 + fk);
    }
#pragma unroll
    for (int i = 0; i < 4; i++)
#pragma unroll
      for (int j = 0; j < 4; j++)
        acc[i][j] = __builtin_amdgcn_mfma_f32_16x16x32_bf16(af[i], bfr[j], acc[i][j], 0, 0, 0);
    __syncthreads();
  }

  int cr = (lane >> 4) * 4;
  int ccl = lane & 15;
#pragma unroll
  for (int i = 0; i < 4; i++) {
#pragma unroll
    for (int j = 0; j < 4; j++) {
      int col = n0 + wc * 64 + j * 16 + ccl;
      float bv = bias[col];
#pragma unroll
      for (int r = 0; r < 4; r++) {
        int row = m0 + wr * 64 + i * 16 + cr + r;
        size_t idx = (size_t)row * Nd + col;
        float val = acc[i][j][r] + bv;
        if (MODE == 1) val += hres[idx] + xres[idx];
        Cout[idx] = val;
      }
    }
  }
}

// ============================================================================
// 256x256 4-phase/K-tile GEMM — EXACT R0 configuration (best measured head:
// 716 us / 751 TF). Six head experiments (nt stores, bn-chunk, 128^2 tile,
// deep pipeline, persistent) all regressed; this config is the proven local
// optimum for NT=16. Do not modify without a within-session A/B.
// ============================================================================
template <int MODE>
__global__ __launch_bounds__(512, 2) void k_gemm256p8(
    const bf16* __restrict__ A, const bf16* __restrict__ BT,
    const float* __restrict__ bias, const float* __restrict__ xres,
    const float* __restrict__ hres, float* __restrict__ Cout,
    int Md, int Nd, int Kd) {
  __shared__ __align__(16) bf16 As[2][16384];  // [buf][256 rows x 64 k]
  __shared__ __align__(16) bf16 Bs[2][16384];

  int gx = gridDim.x;
  int wg = blockIdx.y * gx + blockIdx.x;
  int mch = gx >> 3;                 // bm-chunk per XCD (gx % 8 == 0)
  int xcd = wg & 7;
  int r = wg >> 3;
  int bm = xcd * mch + (r % mch);
  int bn = r / mch;
  int m0 = bm * 256, n0 = bn * 256;

  int tid = threadIdx.x;
  int wid = tid >> 6, lane = tid & 63;
  int wr = wid >> 2, wc = wid & 3;  // interleaved: A row m*32+wr*16, B row n*64+wc*16

  size_t KdS = (size_t)Kd;
  int srow = tid >> 3;                               // 0..63 slab row
  int sk = (((tid & 7) ^ (srow & 7)) << 3);          // source elem offset
  const bf16* aSrc = A + (size_t)(m0 + srow) * KdS + sk;
  const bf16* bSrc = BT + (size_t)(n0 + srow) * KdS + sk;
  int ldst = wid * 512;                              // wave-uniform elem base

#define STAGE_A(buf, h, t)                                                              \
  do {                                                                                  \
    __builtin_amdgcn_global_load_lds(GPTR(aSrc + (size_t)((h) * 128) * KdS + (t) * 64), \
                                     LPTR(&As[buf][(h) * 8192 + ldst]), 16, 0, 0);      \
    __builtin_amdgcn_global_load_lds(                                                   \
        GPTR(aSrc + (size_t)((h) * 128 + 64) * KdS + (t) * 64),                         \
        LPTR(&As[buf][(h) * 8192 + 4096 + ldst]), 16, 0, 0);                            \
  } while (0)
#define STAGE_B(buf, h, t)                                                              \
  do {                                                                                  \
    __builtin_amdgcn_global_load_lds(GPTR(bSrc + (size_t)((h) * 128) * KdS + (t) * 64), \
                                     LPTR(&Bs[buf][(h) * 8192 + ldst]), 16, 0, 0);      \
    __builtin_amdgcn_global_load_lds(                                                   \
        GPTR(bSrc + (size_t)((h) * 128 + 64) * KdS + (t) * 64),                         \
        LPTR(&Bs[buf][(h) * 8192 + 4096 + ldst]), 16, 0, 0);                            \
  } while (0)

  int frow = lane & 15;
  int khi = lane >> 4;   // 0..3
  int rx = frow & 7;
  int lk0 = ((khi) ^ rx) << 3;        // k-window 0 (k 0..31)
  int lk1 = ((4 + khi) ^ rx) << 3;    // k-window 1 (k 32..63)
  int wr16 = wr * 16, wc16 = wc * 16;

  f32x4 acc[8][4];
#pragma unroll
  for (int m = 0; m < 8; m++)
#pragma unroll
    for (int n = 0; n < 4; n++) acc[m][n] = (f32x4){0.f, 0.f, 0.f, 0.f};

  const int NT = Kd >> 6;  // 16 K-tiles of 64

  // ---- prologue: tile0 fully -> buf0 (A0,B0,B1,A1), tile1 A0,B0,B1 -> buf1
  STAGE_A(0, 0, 0);
  STAGE_B(0, 0, 0);
  STAGE_B(0, 1, 0);
  STAGE_A(0, 1, 0);
  STAGE_A(1, 0, 1);
  STAGE_B(1, 0, 1);
  STAGE_B(1, 1, 1);
  asm volatile("s_waitcnt vmcnt(6)" ::: "memory");  // tile0's 8 loads landed
  __builtin_amdgcn_s_barrier();
  __builtin_amdgcn_sched_barrier(0);

  for (int t = 0; t < NT; ++t) {
    int c = t & 1, o = c ^ 1;
    const bf16* Ac = As[c];
    const bf16* Bc = Bs[c];
    bf16x8 a[4][2], b[2][2], b2[2][2];

    // ===== phase 0: read a(m0..3) + b(n0..1); stage A-h1(t+1)->oth; MFMA
#pragma unroll
    for (int m = 0; m < 4; m++) {
      int ro = (m * 32 + wr16 + frow) * 64;
      a[m][0] = *(const bf16x8*)(Ac + ro + lk0);
      a[m][1] = *(const bf16x8*)(Ac + ro + lk1);
    }
#pragma unroll
    for (int n = 0; n < 2; n++) {
      int ro = (n * 64 + wc16 + frow) * 64;
      b[n][0] = *(const bf16x8*)(Bc + ro + lk0);
      b[n][1] = *(const bf16x8*)(Bc + ro + lk1);
    }
    if (t + 1 < NT) STAGE_A(o, 1, t + 1);
    __builtin_amdgcn_s_barrier();
    asm volatile("s_waitcnt lgkmcnt(0)" ::: "memory");
    __builtin_amdgcn_sched_barrier(0);
    __builtin_amdgcn_s_setprio(1);
#pragma unroll
    for (int m = 0; m < 4; m++)
#pragma unroll
      for (int n = 0; n < 2; n++) {
        acc[m][n] = __builtin_amdgcn_mfma_f32_16x16x32_bf16(a[m][0], b[n][0], acc[m][n], 0, 0, 0);
        acc[m][n] = __builtin_amdgcn_mfma_f32_16x16x32_bf16(a[m][1], b[n][1], acc[m][n], 0, 0, 0);
      }
    __builtin_amdgcn_s_setprio(0);
    __builtin_amdgcn_s_barrier();
    __builtin_amdgcn_sched_barrier(0);

    // ===== phase 1: read b2(n2..3); stage A-h0(t+2)->cur; MFMA
#pragma unroll
    for (int n = 0; n < 2; n++) {
      int ro = ((n + 2) * 64 + wc16 + frow) * 64;
      b2[n][0] = *(const bf16x8*)(Bc + ro + lk0);
      b2[n][1] = *(const bf16x8*)(Bc + ro + lk1);
    }
    if (t + 2 < NT) STAGE_A(c, 0, t + 2);
    __builtin_amdgcn_s_barrier();
    asm volatile("s_waitcnt lgkmcnt(0)" ::: "memory");
    __builtin_amdgcn_sched_barrier(0);
    __builtin_amdgcn_s_setprio(1);
#pragma unroll
    for (int m = 0; m < 4; m++)
#pragma unroll
      for (int n = 0; n < 2; n++) {
        acc[m][n + 2] = __builtin_amdgcn_mfma_f32_16x16x32_bf16(a[m][0], b2[n][0], acc[m][n + 2], 0, 0, 0);
        acc[m][n + 2] = __builtin_amdgcn_mfma_f32_16x16x32_bf16(a[m][1], b2[n][1], acc[m][n + 2], 0, 0, 0);
      }
    __builtin_amdgcn_s_setprio(0);
    __builtin_amdgcn_s_barrier();
    __builtin_amdgcn_sched_barrier(0);

    // ===== phase 2: read a(m4..7); stage B-h0(t+2)->cur; MFMA
#pragma unroll
    for (int m = 0; m < 4; m++) {
      int ro = ((m + 4) * 32 + wr16 + frow) * 64;
      a[m][0] = *(const bf16x8*)(Ac + ro + lk0);
      a[m][1] = *(const bf16x8*)(Ac + ro + lk1);
    }
    if (t + 2 < NT) STAGE_B(c, 0, t + 2);
    __builtin_amdgcn_s_barrier();
    asm volatile("s_waitcnt lgkmcnt(0)" ::: "memory");
    __builtin_amdgcn_sched_barrier(0);
    __builtin_amdgcn_s_setprio(1);
#pragma unroll
    for (int m = 0; m < 4; m++)
#pragma unroll
      for (int n = 0; n < 2; n++) {
        acc[m + 4][n] = __builtin_amdgcn_mfma_f32_16x16x32_bf16(a[m][0], b[n][0], acc[m + 4][n], 0, 0, 0);
        acc[m + 4][n] = __builtin_amdgcn_mfma_f32_16x16x32_bf16(a[m][1], b[n][1], acc[m + 4][n], 0, 0, 0);
      }
    __builtin_amdgcn_s_setprio(0);
    __builtin_amdgcn_s_barrier();
    __builtin_amdgcn_sched_barrier(0);

    // ===== phase 3: no reads; stage B-h1(t+2)->cur; MFMA; gate
    if (t + 2 < NT) STAGE_B(c, 1, t + 2);
    __builtin_amdgcn_s_barrier();
    __builtin_amdgcn_sched_barrier(0);
    __builtin_amdgcn_s_setprio(1);
#pragma unroll
    for (int m = 0; m < 4; m++)
#pragma unroll
      for (int n = 0; n < 2; n++) {
        acc[m + 4][n + 2] = __builtin_amdgcn_mfma_f32_16x16x32_bf16(a[m][0], b2[n][0], acc[m + 4][n + 2], 0, 0, 0);
        acc[m + 4][n + 2] = __builtin_amdgcn_mfma_f32_16x16x32_bf16(a[m][1], b2[n][1], acc[m + 4][n + 2], 0, 0, 0);
      }
    __builtin_amdgcn_s_setprio(0);
    if (t < NT - 2) {
      asm volatile("s_waitcnt vmcnt(6)" ::: "memory");  // 3 half-tiles in flight
    } else if (t == NT - 2) {
      asm volatile("s_waitcnt vmcnt(0)" ::: "memory");  // drain for last tile
    }
    __builtin_amdgcn_s_barrier();
    __builtin_amdgcn_sched_barrier(0);
  }
#undef STAGE_A
#undef STAGE_B

  // ---- epilogue (interleaved mapping); plain stores ----
  int cr = (lane >> 4) * 4;
  int ccl = lane & 15;
#pragma unroll
  for (int m = 0; m < 8; m++) {
#pragma unroll
    for (int n = 0; n < 4; n++) {
      int col = n0 + n * 64 + wc16 + ccl;
      float bvv = bias[col];
#pragma unroll
      for (int r2 = 0; r2 < 4; r2++) {
        int row = m0 + m * 32 + wr16 + cr + r2;
        size_t idx = (size_t)row * Nd + col;
        float val = acc[m][n][r2] + bvv;
        if (MODE == 1) val += hres[idx] + xres[idx];
        Cout[idx] = val;
      }
    }
  }
}

extern "C" void kernel_launch(void* const* d_in, const int* in_sizes, int n_in,
                              void* d_out, int out_size, void* d_ws, size_t ws_size,
                              hipStream_t stream) {
  const int* tokens   = (const int*)d_in[0];
  const float* embed  = (const float*)d_in[1];
  const float* ln1_g  = (const float*)d_in[2];
  const float* ln1_b  = (const float*)d_in[3];
  const float* ph1    = (const float*)d_in[4];
  const float* wv1    = (const float*)d_in[5];
  const float* bv1    = (const float*)d_in[6];
  const float* lno1_g = (const float*)d_in[7];
  const float* lno1_b = (const float*)d_in[8];
  const float* wo1    = (const float*)d_in[9];
  const float* bo1    = (const float*)d_in[10];
  const float* ln2_g  = (const float*)d_in[11];
  const float* ln2_b  = (const float*)d_in[12];
  const float* ph2    = (const float*)d_in[13];
  const float* wv2    = (const float*)d_in[14];
  const float* bv2    = (const float*)d_in[15];
  const float* lno2_g = (const float*)d_in[16];
  const float* lno2_b = (const float*)d_in[17];
  const float* wo2    = (const float*)d_in[18];
  const float* bo2    = (const float*)d_in[19];
  const float* ln3_g  = (const float*)d_in[20];
  const float* ln3_b  = (const float*)d_in[21];
  const float* w_head = (const float*)d_in[22];
  const float* b_head = (const float*)d_in[23];

  float* out = (float*)d_out;

  // ws: bf16 weights (transposed) + bf16 LN output  (~91 MB)
  char* ws = (char*)d_ws;
  bf16* whT  = (bf16*)ws;                    // [V][D]
  bf16* wv1T = whT + (size_t)kV * kD;        // [D][D] each
  bf16* wo1T = wv1T + (size_t)kD * kD;
  bf16* wv2T = wo1T + (size_t)kD * kD;
  bf16* wo2T = wv2T + (size_t)kD * kD;
  bf16* xb   = wo2T + (size_t)kD * kD;       // [M][D] bf16 (LN output, reused)

  // f32 activations live in d_out (1 GB); fully overwritten by the final GEMM
  float* h  = out;                            // [M][D]
  float* xf = h + (size_t)kM * kD;            // [M][D]
  float* vb = xf + (size_t)kM * kD;           // [M][D] v / retrieved (in-place)
  float* ct = vb + (size_t)kM * kD;           // [L][D]
  float* st = ct + (size_t)kL * kD;           // [L][D]
  float* pr = st + (size_t)kL * kD;           // [B][NC][D]
  float* pi = pr + (size_t)kB * kNC * kD;

  // weight conversion (transpose to [N][K] bf16), 64x64 vectorized tiles
  k_tcvt64<<<dim3(kD / 64, kD / 64), 256, 0, stream>>>(wv1, wv1T, kD, kD);
  k_tcvt64<<<dim3(kD / 64, kD / 64), 256, 0, stream>>>(wo1, wo1T, kD, kD);
  k_tcvt64<<<dim3(kD / 64, kD / 64), 256, 0, stream>>>(wv2, wv2T, kD, kD);
  k_tcvt64<<<dim3(kD / 64, kD / 64), 256, 0, stream>>>(wo2, wo2T, kD, kD);
  k_tcvt64<<<dim3(kV / 64, kD / 64), 256, 0, stream>>>(w_head, whT, kD, kV);

  const int scanBlocks = kB * kNC * kD / 256;  // 256

  // ---- phasor block 1 ----
  k_sincos<<<(kL * kD + 255) / 256, 256, 0, stream>>>(ph1, ct, st, kL * kD);
  k_embln<<<kM, 256, 0, stream>>>(tokens, embed, ln1_g, ln1_b, h, xb, xf);
  k_gemm_bt<0><<<dim3(kM / 128, kD / 128), 256, 0, stream>>>(xb, wv1T, bv1, nullptr, nullptr,
                                                             vb, kM, kD, kD);
  k_scan_part<<<scanBlocks, 256, 0, stream>>>(vb, ct, st, pr, pi);
  k_scan_apply<<<scanBlocks, 256, 0, stream>>>(vb, ct, st, pr, pi);
  k_ln<false><<<kM, 256, 0, stream>>>(vb, lno1_g, lno1_b, xb, nullptr);
  k_gemm_bt<1><<<dim3(kM / 128, kD / 128), 256, 0, stream>>>(xb, wo1T, bo1, xf, h,
                                                             h, kM, kD, kD);

  // ---- phasor block 2 ----
  k_sincos<<<(kL * kD + 255) / 256, 256, 0, stream>>>(ph2, ct, st, kL * kD);
  k_ln<true><<<kM, 256, 0, stream>>>(h, ln2_g, ln2_b, xb, xf);
  k_gemm_bt<0><<<dim3(kM / 128, kD / 128), 256, 0, stream>>>(xb, wv2T, bv2, nullptr, nullptr,
                                                             vb, kM, kD, kD);
  k_scan_part<<<scanBlocks, 256, 0, stream>>>(vb, ct, st, pr, pi);
  k_scan_apply<<<scanBlocks, 256, 0, stream>>>(vb, ct, st, pr, pi);
  k_ln<false><<<kM, 256, 0, stream>>>(vb, lno2_g, lno2_b, xb, nullptr);
  k_gemm_bt<1><<<dim3(kM / 128, kD / 128), 256, 0, stream>>>(xb, wo2T, bo2, xf, h,
                                                             h, kM, kD, kD);

  // ---- final LN + head GEMM (EXACT R0 config: 256^2, 4-phase, bm-chunked) ----
  k_ln<false><<<kM, 256, 0, stream>>>(h, ln3_g, ln3_b, xb, nullptr);
  k_gemm256p8<0><<<dim3(kM / 256, kV / 256), 512, 0, stream>>>(xb, whT, b_head, nullptr,
                                                               nullptr, out, kM, kV, kD);
}

// Round 7
// 1041.962 us; speedup vs baseline: 1.1466x; 1.0124x over previous
//
#include <hip/hip_runtime.h>
#include <hip/hip_bf16.h>
#include <math.h>

typedef __hip_bfloat16 bf16;
typedef __attribute__((ext_vector_type(8))) short bf16x8;
typedef __attribute__((ext_vector_type(4))) float f32x4;

#define GPTR(p) ((__attribute__((address_space(1))) void*)(void*)(p))
#define LPTR(p) ((__attribute__((address_space(3))) void*)(void*)(p))

static constexpr int kB = 4, kL = 2048, kD = 1024, kV = 32000;
static constexpr int kM = kB * kL;                 // 8192
static constexpr int kNC = 16, kCH = kL / kNC;     // 16 chunks of 128

// ---------------- sincos tables ----------------
__global__ void k_sincos(const float* __restrict__ ph, float* __restrict__ c,
                         float* __restrict__ s, int n) {
  int i = blockIdx.x * 256 + threadIdx.x;
  if (i < n) {
    float sv, cv;
    sincosf(ph[i], &sv, &cv);
    c[i] = cv;
    s[i] = sv;
  }
}

// ---------------- transpose + f32 -> bf16 : in[R][C] -> out[C][R] ----------------
__global__ void k_tcvt64(const float* __restrict__ in, bf16* __restrict__ out,
                         int R, int C) {
  __shared__ bf16 tile[64][66];
  int c0 = blockIdx.x * 64, r0 = blockIdx.y * 64;
  int tid = threadIdx.x;  // 256
  int cq = tid & 15;
  int rr = tid >> 4;
#pragma unroll
  for (int i = 0; i < 4; i++) {
    int r = rr + i * 16;
    float4 v = *(const float4*)(in + (size_t)(r0 + r) * C + c0 + cq * 4);
    tile[r][cq * 4 + 0] = __float2bfloat16(v.x);
    tile[r][cq * 4 + 1] = __float2bfloat16(v.y);
    tile[r][cq * 4 + 2] = __float2bfloat16(v.z);
    tile[r][cq * 4 + 3] = __float2bfloat16(v.w);
  }
  __syncthreads();
  int rb = tid & 7;
  int cc = tid >> 3;
#pragma unroll
  for (int i = 0; i < 2; i++) {
    int c = cc + i * 32;
    bf16x8 p;
#pragma unroll
    for (int j = 0; j < 8; j++) p[j] = *(const short*)&tile[rb * 8 + j][c];
    *(bf16x8*)(out + (size_t)(c0 + c) * R + r0 + rb * 8) = p;
  }
}

// ---------------- fused embedding gather + layernorm (row = blockIdx) ----------
__global__ void k_embln(const int* __restrict__ tok, const float* __restrict__ emb,
                        const float* __restrict__ g, const float* __restrict__ b,
                        float* __restrict__ h, bf16* __restrict__ ob,
                        float* __restrict__ of) {
  int row = blockIdx.x;
  int tid = threadIdx.x;
  int t = tok[row];
  float4 v = ((const float4*)(emb + (size_t)t * kD))[tid];
  ((float4*)(h + (size_t)row * kD))[tid] = v;  // raw embed (residual source)
  float sum = v.x + v.y + v.z + v.w;
  float sq = fmaf(v.x, v.x, fmaf(v.y, v.y, fmaf(v.z, v.z, v.w * v.w)));
#pragma unroll
  for (int o = 32; o > 0; o >>= 1) {
    sum += __shfl_down(sum, o);
    sq += __shfl_down(sq, o);
  }
  __shared__ float ss[4], sk[4];
  int w = tid >> 6;
  if ((tid & 63) == 0) { ss[w] = sum; sk[w] = sq; }
  __syncthreads();
  float ts = ss[0] + ss[1] + ss[2] + ss[3];
  float tq = sk[0] + sk[1] + sk[2] + sk[3];
  float mu = ts * (1.0f / kD);
  float var = tq * (1.0f / kD) - mu * mu;
  float rstd = rsqrtf(var + 1e-5f);
  float4 gg = ((const float4*)g)[tid];
  float4 bb = ((const float4*)b)[tid];
  float4 o;
  o.x = fmaf((v.x - mu) * rstd, gg.x, bb.x);
  o.y = fmaf((v.y - mu) * rstd, gg.y, bb.y);
  o.z = fmaf((v.z - mu) * rstd, gg.z, bb.z);
  o.w = fmaf((v.w - mu) * rstd, gg.w, bb.w);
  union { ushort4 u; bf16 hh[4]; } pk;
  pk.hh[0] = __float2bfloat16(o.x);
  pk.hh[1] = __float2bfloat16(o.y);
  pk.hh[2] = __float2bfloat16(o.z);
  pk.hh[3] = __float2bfloat16(o.w);
  *(ushort4*)(ob + (size_t)row * kD + tid * 4) = pk.u;
  ((float4*)(of + (size_t)row * kD))[tid] = o;
}

// ---------------- row layernorm (D=1024), 256 threads/row ----------------
template <bool WF32>
__global__ void k_ln(const float* __restrict__ in, const float* __restrict__ g,
                     const float* __restrict__ b, bf16* __restrict__ ob,
                     float* __restrict__ of) {
  int row = blockIdx.x;
  int tid = threadIdx.x;
  const float4* x4 = (const float4*)(in + (size_t)row * kD);
  float4 v = x4[tid];
  float sum = v.x + v.y + v.z + v.w;
  float sq = fmaf(v.x, v.x, fmaf(v.y, v.y, fmaf(v.z, v.z, v.w * v.w)));
#pragma unroll
  for (int o = 32; o > 0; o >>= 1) {
    sum += __shfl_down(sum, o);
    sq += __shfl_down(sq, o);
  }
  __shared__ float ss[4], sk[4];
  int w = tid >> 6;
  if ((tid & 63) == 0) { ss[w] = sum; sk[w] = sq; }
  __syncthreads();
  float ts = ss[0] + ss[1] + ss[2] + ss[3];
  float tq = sk[0] + sk[1] + sk[2] + sk[3];
  float mu = ts * (1.0f / kD);
  float var = tq * (1.0f / kD) - mu * mu;
  float rstd = rsqrtf(var + 1e-5f);
  float4 gg = ((const float4*)g)[tid];
  float4 bb = ((const float4*)b)[tid];
  float4 o;
  o.x = fmaf((v.x - mu) * rstd, gg.x, bb.x);
  o.y = fmaf((v.y - mu) * rstd, gg.y, bb.y);
  o.z = fmaf((v.z - mu) * rstd, gg.z, bb.z);
  o.w = fmaf((v.w - mu) * rstd, gg.w, bb.w);
  union { ushort4 u; bf16 h[4]; } pk;
  pk.h[0] = __float2bfloat16(o.x);
  pk.h[1] = __float2bfloat16(o.y);
  pk.h[2] = __float2bfloat16(o.z);
  pk.h[3] = __float2bfloat16(o.w);
  *(ushort4*)(ob + (size_t)row * kD + tid * 4) = pk.u;
  if constexpr (WF32) {
    ((float4*)(of + (size_t)row * kD))[tid] = o;
  }
}

// ---------------- phasor scan: pass A (chunk partial sums) ----------------
__global__ void k_scan_part(const float* __restrict__ v, const float* __restrict__ c,
                            const float* __restrict__ s, float* __restrict__ pr,
                            float* __restrict__ pi) {
  int tid = blockIdx.x * 256 + threadIdx.x;  // b*16384 + ch*1024 + d
  int d = tid & (kD - 1);
  int ch = (tid >> 10) & (kNC - 1);
  int b = tid >> 14;
  const float* vp = v + ((size_t)b * kL + ch * kCH) * kD + d;
  const float* cp = c + (size_t)(ch * kCH) * kD + d;
  const float* sp = s + (size_t)(ch * kCH) * kD + d;
  float ar = 0.f, ai = 0.f;
  for (int i = 0; i < kCH; i++) {
    float vv = vp[i * kD];
    ar = fmaf(vv, cp[i * kD], ar);
    ai = fmaf(vv, sp[i * kD], ai);
  }
  pr[tid] = ar;
  pi[tid] = ai;
}

// ---------------- phasor scan: pass B (apply, in-place over v) ----------------
__global__ void k_scan_apply(float* __restrict__ v, const float* __restrict__ c,
                             const float* __restrict__ s, const float* __restrict__ pr,
                             const float* __restrict__ pi) {
  int tid = blockIdx.x * 256 + threadIdx.x;
  int d = tid & (kD - 1);
  int ch = (tid >> 10) & (kNC - 1);
  int b = tid >> 14;
  float ar = 0.f, ai = 0.f;
  int pbase = (b << 14) + d;
  for (int cc = 0; cc < ch; cc++) {
    ar += pr[pbase + cc * kD];
    ai += pi[pbase + cc * kD];
  }
  float* vp = v + ((size_t)b * kL + ch * kCH) * kD + d;
  const float* cp = c + (size_t)(ch * kCH) * kD + d;
  const float* sp = s + (size_t)(ch * kCH) * kD + d;
  for (int i = 0; i < kCH; i++) {
    float vv = vp[i * kD];
    float cv = cp[i * kD], sv = sp[i * kD];
    ar = fmaf(vv, cv, ar);
    ai = fmaf(vv, sv, ai);
    vp[i * kD] = (ar * cv + ai * sv) * 0.03125f;  // 1/sqrt(1024)
  }
}

// ---------------- 128x128-tile GEMM (R0 config, proven) for small D x D ----
template <int MODE>
__global__ __launch_bounds__(256) void k_gemm_bt(
    const bf16* __restrict__ A, const bf16* __restrict__ BT,
    const float* __restrict__ bias, const float* __restrict__ xres,
    const float* __restrict__ hres, float* __restrict__ Cout,
    int Md, int Nd, int Kd) {
  __shared__ __align__(16) bf16 As[128 * 32];
  __shared__ __align__(16) bf16 Bs[128 * 32];
  int nwg = gridDim.x * gridDim.y;
  int wg = blockIdx.y * gridDim.x + blockIdx.x;
  int per = nwg >> 3;
  int sw = (wg & 7) * per + (wg >> 3);
  int bm = sw % gridDim.x;
  int bn = sw / gridDim.x;
  int m0 = bm * 128, n0 = bn * 128;
  int tid = threadIdx.x;
  int wid = tid >> 6, lane = tid & 63;
  int wr = wid >> 1, wc = wid & 1;

  f32x4 acc[4][4];
#pragma unroll
  for (int i = 0; i < 4; i++)
#pragma unroll
    for (int j = 0; j < 4; j++) acc[i][j] = (f32x4){0.f, 0.f, 0.f, 0.f};

  const bf16* Abase = A + (size_t)m0 * Kd;
  const bf16* Bbase = BT + (size_t)n0 * Kd;
  int lr = lane >> 2;
  int lk = (lane & 3) * 8;
  int frow = lane & 15;
  int fk = (lane >> 4) * 8;

  for (int k0 = 0; k0 < Kd; k0 += 32) {
#pragma unroll
    for (int c = 0; c < 2; c++) {
      int ch = wid + c * 4;
      __builtin_amdgcn_global_load_lds(GPTR(Abase + (size_t)(ch * 16 + lr) * Kd + k0 + lk),
                                       LPTR(As + ch * 512), 16, 0, 0);
      __builtin_amdgcn_global_load_lds(GPTR(Bbase + (size_t)(ch * 16 + lr) * Kd + k0 + lk),
                                       LPTR(Bs + ch * 512), 16, 0, 0);
    }
    asm volatile("s_waitcnt vmcnt(0)" ::: "memory");
    __syncthreads();
    bf16x8 af[4], bfr[4];
#pragma unroll
    for (int i = 0; i < 4; i++) {
      af[i] = *(const bf16x8*)(As + (wr * 64 + i * 16 + frow) * 32 + fk);
      bfr[i] = *(const bf16x8*)(Bs + (wc * 64 + i * 16 + frow) * 32 + fk);
    }
#pragma unroll
    for (int i = 0; i < 4; i++)
#pragma unroll
      for (int j = 0; j < 4; j++)
        acc[i][j] = __builtin_amdgcn_mfma_f32_16x16x32_bf16(af[i], bfr[j], acc[i][j], 0, 0, 0);
    __syncthreads();
  }

  int cr = (lane >> 4) * 4;
  int ccl = lane & 15;
#pragma unroll
  for (int i = 0; i < 4; i++) {
#pragma unroll
    for (int j = 0; j < 4; j++) {
      int col = n0 + wc * 64 + j * 16 + ccl;
      float bv = bias[col];
#pragma unroll
      for (int r = 0; r < 4; r++) {
        int row = m0 + wr * 64 + i * 16 + cr + r;
        size_t idx = (size_t)row * Nd + col;
        float val = acc[i][j][r] + bv;
        if (MODE == 1) val += hres[idx] + xres[idx];
        Cout[idx] = val;
      }
    }
  }
}

// ============================================================================
// 256x256 4-phase/K-tile head GEMM. R7 = R0/R6 K-loop (proven 716 us) +:
//  (a) per-wave CONTIGUOUS 64-col B mapping: B rows read at wc*64 + n*16
//      (was n*64 + wc*16). Bijective wave->column relabeling; LDS read
//      pattern & conflicts unchanged (same row&7 distribution). Each 128B
//      C-line's two 64B halves are now written by the SAME wave 4 stores
//      apart -> L2 write-combines them.
//  (b) NT stores in the epilogue. Rounds 0-6 decomposition: every
//      plain-store round has (total - head) = 334-354 us; the one nt round
//      (R1) = 273 us -- the head's 1 GB plain C-write flushes L3 each graph
//      iteration, penalizing the next iteration's leading kernels. R1 paid
//      +33 us head for partial-line writebacks (WRITE 1.03->1.27 GB, cross-
//      wave half-lines); (a) removes that cost.
//  Falsifiable: WRITE_SIZE must be ~1.03e6 (not 1.26e6) and head ~716-730.
// ============================================================================
template <int MODE>
__global__ __launch_bounds__(512, 2) void k_gemm256p8(
    const bf16* __restrict__ A, const bf16* __restrict__ BT,
    const float* __restrict__ bias, const float* __restrict__ xres,
    const float* __restrict__ hres, float* __restrict__ Cout,
    int Md, int Nd, int Kd) {
  __shared__ __align__(16) bf16 As[2][16384];  // [buf][256 rows x 64 k]
  __shared__ __align__(16) bf16 Bs[2][16384];

  int gx = gridDim.x;
  int wg = blockIdx.y * gx + blockIdx.x;
  int mch = gx >> 3;                 // bm-chunk per XCD (gx % 8 == 0)
  int xcd = wg & 7;
  int r = wg >> 3;
  int bm = xcd * mch + (r % mch);
  int bn = r / mch;
  int m0 = bm * 256, n0 = bn * 256;

  int tid = threadIdx.x;
  int wid = tid >> 6, lane = tid & 63;
  int wr = wid >> 2, wc = wid & 3;  // A row m*32+wr*16; B col block wc*64 (contiguous)

  size_t KdS = (size_t)Kd;
  int srow = tid >> 3;                               // 0..63 slab row
  int sk = (((tid & 7) ^ (srow & 7)) << 3);          // source elem offset
  const bf16* aSrc = A + (size_t)(m0 + srow) * KdS + sk;
  const bf16* bSrc = BT + (size_t)(n0 + srow) * KdS + sk;
  int ldst = wid * 512;                              // wave-uniform elem base

#define STAGE_A(buf, h, t)                                                              \
  do {                                                                                  \
    __builtin_amdgcn_global_load_lds(GPTR(aSrc + (size_t)((h) * 128) * KdS + (t) * 64), \
                                     LPTR(&As[buf][(h) * 8192 + ldst]), 16, 0, 0);      \
    __builtin_amdgcn_global_load_lds(                                                   \
        GPTR(aSrc + (size_t)((h) * 128 + 64) * KdS + (t) * 64),                         \
        LPTR(&As[buf][(h) * 8192 + 4096 + ldst]), 16, 0, 0);                            \
  } while (0)
#define STAGE_B(buf, h, t)                                                              \
  do {                                                                                  \
    __builtin_amdgcn_global_load_lds(GPTR(bSrc + (size_t)((h) * 128) * KdS + (t) * 64), \
                                     LPTR(&Bs[buf][(h) * 8192 + ldst]), 16, 0, 0);      \
    __builtin_amdgcn_global_load_lds(                                                   \
        GPTR(bSrc + (size_t)((h) * 128 + 64) * KdS + (t) * 64),                         \
        LPTR(&Bs[buf][(h) * 8192 + 4096 + ldst]), 16, 0, 0);                            \
  } while (0)

  int frow = lane & 15;
  int khi = lane >> 4;   // 0..3
  int rx = frow & 7;
  int lk0 = ((khi) ^ rx) << 3;        // k-window 0 (k 0..31)
  int lk1 = ((4 + khi) ^ rx) << 3;    // k-window 1 (k 32..63)
  int wr16 = wr * 16;
  int wc64 = wc * 64;                 // contiguous 64-col block per wave

  f32x4 acc[8][4];
#pragma unroll
  for (int m = 0; m < 8; m++)
#pragma unroll
    for (int n = 0; n < 4; n++) acc[m][n] = (f32x4){0.f, 0.f, 0.f, 0.f};

  const int NT = Kd >> 6;  // 16 K-tiles of 64

  // ---- prologue: tile0 fully -> buf0 (A0,B0,B1,A1), tile1 A0,B0,B1 -> buf1
  STAGE_A(0, 0, 0);
  STAGE_B(0, 0, 0);
  STAGE_B(0, 1, 0);
  STAGE_A(0, 1, 0);
  STAGE_A(1, 0, 1);
  STAGE_B(1, 0, 1);
  STAGE_B(1, 1, 1);
  asm volatile("s_waitcnt vmcnt(6)" ::: "memory");  // tile0's 8 loads landed
  __builtin_amdgcn_s_barrier();
  __builtin_amdgcn_sched_barrier(0);

  for (int t = 0; t < NT; ++t) {
    int c = t & 1, o = c ^ 1;
    const bf16* Ac = As[c];
    const bf16* Bc = Bs[c];
    bf16x8 a[4][2], b[2][2], b2[2][2];

    // ===== phase 0: read a(m0..3) + b(n0..1); stage A-h1(t+1)->oth; MFMA
#pragma unroll
    for (int m = 0; m < 4; m++) {
      int ro = (m * 32 + wr16 + frow) * 64;
      a[m][0] = *(const bf16x8*)(Ac + ro + lk0);
      a[m][1] = *(const bf16x8*)(Ac + ro + lk1);
    }
#pragma unroll
    for (int n = 0; n < 2; n++) {
      int ro = (wc64 + n * 16 + frow) * 64;
      b[n][0] = *(const bf16x8*)(Bc + ro + lk0);
      b[n][1] = *(const bf16x8*)(Bc + ro + lk1);
    }
    if (t + 1 < NT) STAGE_A(o, 1, t + 1);
    __builtin_amdgcn_s_barrier();
    asm volatile("s_waitcnt lgkmcnt(0)" ::: "memory");
    __builtin_amdgcn_sched_barrier(0);
    __builtin_amdgcn_s_setprio(1);
#pragma unroll
    for (int m = 0; m < 4; m++)
#pragma unroll
      for (int n = 0; n < 2; n++) {
        acc[m][n] = __builtin_amdgcn_mfma_f32_16x16x32_bf16(a[m][0], b[n][0], acc[m][n], 0, 0, 0);
        acc[m][n] = __builtin_amdgcn_mfma_f32_16x16x32_bf16(a[m][1], b[n][1], acc[m][n], 0, 0, 0);
      }
    __builtin_amdgcn_s_setprio(0);
    __builtin_amdgcn_s_barrier();
    __builtin_amdgcn_sched_barrier(0);

    // ===== phase 1: read b2(n2..3); stage A-h0(t+2)->cur; MFMA
#pragma unroll
    for (int n = 0; n < 2; n++) {
      int ro = (wc64 + (n + 2) * 16 + frow) * 64;
      b2[n][0] = *(const bf16x8*)(Bc + ro + lk0);
      b2[n][1] = *(const bf16x8*)(Bc + ro + lk1);
    }
    if (t + 2 < NT) STAGE_A(c, 0, t + 2);
    __builtin_amdgcn_s_barrier();
    asm volatile("s_waitcnt lgkmcnt(0)" ::: "memory");
    __builtin_amdgcn_sched_barrier(0);
    __builtin_amdgcn_s_setprio(1);
#pragma unroll
    for (int m = 0; m < 4; m++)
#pragma unroll
      for (int n = 0; n < 2; n++) {
        acc[m][n + 2] = __builtin_amdgcn_mfma_f32_16x16x32_bf16(a[m][0], b2[n][0], acc[m][n + 2], 0, 0, 0);
        acc[m][n + 2] = __builtin_amdgcn_mfma_f32_16x16x32_bf16(a[m][1], b2[n][1], acc[m][n + 2], 0, 0, 0);
      }
    __builtin_amdgcn_s_setprio(0);
    __builtin_amdgcn_s_barrier();
    __builtin_amdgcn_sched_barrier(0);

    // ===== phase 2: read a(m4..7); stage B-h0(t+2)->cur; MFMA
#pragma unroll
    for (int m = 0; m < 4; m++) {
      int ro = ((m + 4) * 32 + wr16 + frow) * 64;
      a[m][0] = *(const bf16x8*)(Ac + ro + lk0);
      a[m][1] = *(const bf16x8*)(Ac + ro + lk1);
    }
    if (t + 2 < NT) STAGE_B(c, 0, t + 2);
    __builtin_amdgcn_s_barrier();
    asm volatile("s_waitcnt lgkmcnt(0)" ::: "memory");
    __builtin_amdgcn_sched_barrier(0);
    __builtin_amdgcn_s_setprio(1);
#pragma unroll
    for (int m = 0; m < 4; m++)
#pragma unroll
      for (int n = 0; n < 2; n++) {
        acc[m + 4][n] = __builtin_amdgcn_mfma_f32_16x16x32_bf16(a[m][0], b[n][0], acc[m + 4][n], 0, 0, 0);
        acc[m + 4][n] = __builtin_amdgcn_mfma_f32_16x16x32_bf16(a[m][1], b[n][1], acc[m + 4][n], 0, 0, 0);
      }
    __builtin_amdgcn_s_setprio(0);
    __builtin_amdgcn_s_barrier();
    __builtin_amdgcn_sched_barrier(0);

    // ===== phase 3: no reads; stage B-h1(t+2)->cur; MFMA; gate
    if (t + 2 < NT) STAGE_B(c, 1, t + 2);
    __builtin_amdgcn_s_barrier();
    __builtin_amdgcn_sched_barrier(0);
    __builtin_amdgcn_s_setprio(1);
#pragma unroll
    for (int m = 0; m < 4; m++)
#pragma unroll
      for (int n = 0; n < 2; n++) {
        acc[m + 4][n + 2] = __builtin_amdgcn_mfma_f32_16x16x32_bf16(a[m][0], b2[n][0], acc[m + 4][n + 2], 0, 0, 0);
        acc[m + 4][n + 2] = __builtin_amdgcn_mfma_f32_16x16x32_bf16(a[m][1], b2[n][1], acc[m + 4][n + 2], 0, 0, 0);
      }
    __builtin_amdgcn_s_setprio(0);
    if (t < NT - 2) {
      asm volatile("s_waitcnt vmcnt(6)" ::: "memory");  // 3 half-tiles in flight
    } else if (t == NT - 2) {
      asm volatile("s_waitcnt vmcnt(0)" ::: "memory");  // drain for last tile
    }
    __builtin_amdgcn_s_barrier();
    __builtin_amdgcn_sched_barrier(0);
  }
#undef STAGE_A
#undef STAGE_B

  // ---- epilogue: per-wave contiguous 64-col block; nt stores (full lines
  //      per wave -> no partial-line writebacks; write stream skips L2/L3).
  int cr = (lane >> 4) * 4;
  int ccl = lane & 15;
#pragma unroll
  for (int m = 0; m < 8; m++) {
#pragma unroll
    for (int n = 0; n < 4; n++) {
      int col = n0 + wc64 + n * 16 + ccl;
      float bvv = bias[col];
#pragma unroll
      for (int r2 = 0; r2 < 4; r2++) {
        int row = m0 + m * 32 + wr16 + cr + r2;
        size_t idx = (size_t)row * Nd + col;
        float val = acc[m][n][r2] + bvv;
        if (MODE == 1) val += hres[idx] + xres[idx];
        __builtin_nontemporal_store(val, &Cout[idx]);
      }
    }
  }
}

extern "C" void kernel_launch(void* const* d_in, const int* in_sizes, int n_in,
                              void* d_out, int out_size, void* d_ws, size_t ws_size,
                              hipStream_t stream) {
  const int* tokens   = (const int*)d_in[0];
  const float* embed  = (const float*)d_in[1];
  const float* ln1_g  = (const float*)d_in[2];
  const float* ln1_b  = (const float*)d_in[3];
  const float* ph1    = (const float*)d_in[4];
  const float* wv1    = (const float*)d_in[5];
  const float* bv1    = (const float*)d_in[6];
  const float* lno1_g = (const float*)d_in[7];
  const float* lno1_b = (const float*)d_in[8];
  const float* wo1    = (const float*)d_in[9];
  const float* bo1    = (const float*)d_in[10];
  const float* ln2_g  = (const float*)d_in[11];
  const float* ln2_b  = (const float*)d_in[12];
  const float* ph2    = (const float*)d_in[13];
  const float* wv2    = (const float*)d_in[14];
  const float* bv2    = (const float*)d_in[15];
  const float* lno2_g = (const float*)d_in[16];
  const float* lno2_b = (const float*)d_in[17];
  const float* wo2    = (const float*)d_in[18];
  const float* bo2    = (const float*)d_in[19];
  const float* ln3_g  = (const float*)d_in[20];
  const float* ln3_b  = (const float*)d_in[21];
  const float* w_head = (const float*)d_in[22];
  const float* b_head = (const float*)d_in[23];

  float* out = (float*)d_out;

  // ws: bf16 weights (transposed) + bf16 LN output  (~91 MB)
  char* ws = (char*)d_ws;
  bf16* whT  = (bf16*)ws;                    // [V][D]
  bf16* wv1T = whT + (size_t)kV * kD;        // [D][D] each
  bf16* wo1T = wv1T + (size_t)kD * kD;
  bf16* wv2T = wo1T + (size_t)kD * kD;
  bf16* wo2T = wv2T + (size_t)kD * kD;
  bf16* xb   = wo2T + (size_t)kD * kD;       // [M][D] bf16 (LN output, reused)

  // f32 activations live in d_out (1 GB); fully overwritten by the final GEMM
  float* h  = out;                            // [M][D]
  float* xf = h + (size_t)kM * kD;            // [M][D]
  float* vb = xf + (size_t)kM * kD;           // [M][D] v / retrieved (in-place)
  float* ct = vb + (size_t)kM * kD;           // [L][D]
  float* st = ct + (size_t)kL * kD;           // [L][D]
  float* pr = st + (size_t)kL * kD;           // [B][NC][D]
  float* pi = pr + (size_t)kB * kNC * kD;

  // weight conversion (transpose to [N][K] bf16), 64x64 vectorized tiles
  k_tcvt64<<<dim3(kD / 64, kD / 64), 256, 0, stream>>>(wv1, wv1T, kD, kD);
  k_tcvt64<<<dim3(kD / 64, kD / 64), 256, 0, stream>>>(wo1, wo1T, kD, kD);
  k_tcvt64<<<dim3(kD / 64, kD / 64), 256, 0, stream>>>(wv2, wv2T, kD, kD);
  k_tcvt64<<<dim3(kD / 64, kD / 64), 256, 0, stream>>>(wo2, wo2T, kD, kD);
  k_tcvt64<<<dim3(kV / 64, kD / 64), 256, 0, stream>>>(w_head, whT, kD, kV);

  const int scanBlocks = kB * kNC * kD / 256;  // 256

  // ---- phasor block 1 ----
  k_sincos<<<(kL * kD + 255) / 256, 256, 0, stream>>>(ph1, ct, st, kL * kD);
  k_embln<<<kM, 256, 0, stream>>>(tokens, embed, ln1_g, ln1_b, h, xb, xf);
  k_gemm_bt<0><<<dim3(kM / 128, kD / 128), 256, 0, stream>>>(xb, wv1T, bv1, nullptr, nullptr,
                                                             vb, kM, kD, kD);
  k_scan_part<<<scanBlocks, 256, 0, stream>>>(vb, ct, st, pr, pi);
  k_scan_apply<<<scanBlocks, 256, 0, stream>>>(vb, ct, st, pr, pi);
  k_ln<false><<<kM, 256, 0, stream>>>(vb, lno1_g, lno1_b, xb, nullptr);
  k_gemm_bt<1><<<dim3(kM / 128, kD / 128), 256, 0, stream>>>(xb, wo1T, bo1, xf, h,
                                                             h, kM, kD, kD);

  // ---- phasor block 2 ----
  k_sincos<<<(kL * kD + 255) / 256, 256, 0, stream>>>(ph2, ct, st, kL * kD);
  k_ln<true><<<kM, 256, 0, stream>>>(h, ln2_g, ln2_b, xb, xf);
  k_gemm_bt<0><<<dim3(kM / 128, kD / 128), 256, 0, stream>>>(xb, wv2T, bv2, nullptr, nullptr,
                                                             vb, kM, kD, kD);
  k_scan_part<<<scanBlocks, 256, 0, stream>>>(vb, ct, st, pr, pi);
  k_scan_apply<<<scanBlocks, 256, 0, stream>>>(vb, ct, st, pr, pi);
  k_ln<false><<<kM, 256, 0, stream>>>(vb, lno2_g, lno2_b, xb, nullptr);
  k_gemm_bt<1><<<dim3(kM / 128, kD / 128), 256, 0, stream>>>(xb, wo2T, bo2, xf, h,
                                                             h, kM, kD, kD);

  // ---- final LN + head GEMM (R0 K-loop + contiguous-col waves + nt stores) ----
  k_ln<false><<<kM, 256, 0, stream>>>(h, ln3_g, ln3_b, xb, nullptr);
  k_gemm256p8<0><<<dim3(kM / 256, kV / 256), 512, 0, stream>>>(xb, whT, b_head, nullptr,
                                                               nullptr, out, kM, kV, kD);
}

// Round 9
// 962.297 us; speedup vs baseline: 1.2415x; 1.0828x over previous
//
#include <hip/hip_runtime.h>
#include <hip/hip_bf16.h>
#include <math.h>

typedef __hip_bfloat16 bf16;
typedef __attribute__((ext_vector_type(8))) short bf16x8;
typedef __attribute__((ext_vector_type(4))) float f32x4;

#define GPTR(p) ((__attribute__((address_space(1))) void*)(void*)(p))
#define LPTR(p) ((__attribute__((address_space(3))) void*)(void*)(p))

static constexpr int kB = 4, kL = 2048, kD = 1024, kV = 32000;
static constexpr int kM = kB * kL;                 // 8192
static constexpr int kNC = 16, kCH = kL / kNC;     // 16 chunks of 128

// ---------------- sincos tables ----------------
__global__ void k_sincos(const float* __restrict__ ph, float* __restrict__ c,
                         float* __restrict__ s, int n) {
  int i = blockIdx.x * 256 + threadIdx.x;
  if (i < n) {
    float sv, cv;
    sincosf(ph[i], &sv, &cv);
    c[i] = cv;
    s[i] = sv;
  }
}

// ---------------- transpose + f32 -> bf16 : in[R][C] -> out[C][R] ----------------
__global__ void k_tcvt64(const float* __restrict__ in, bf16* __restrict__ out,
                         int R, int C) {
  __shared__ bf16 tile[64][66];
  int c0 = blockIdx.x * 64, r0 = blockIdx.y * 64;
  int tid = threadIdx.x;  // 256
  int cq = tid & 15;
  int rr = tid >> 4;
#pragma unroll
  for (int i = 0; i < 4; i++) {
    int r = rr + i * 16;
    float4 v = *(const float4*)(in + (size_t)(r0 + r) * C + c0 + cq * 4);
    tile[r][cq * 4 + 0] = __float2bfloat16(v.x);
    tile[r][cq * 4 + 1] = __float2bfloat16(v.y);
    tile[r][cq * 4 + 2] = __float2bfloat16(v.z);
    tile[r][cq * 4 + 3] = __float2bfloat16(v.w);
  }
  __syncthreads();
  int rb = tid & 7;
  int cc = tid >> 3;
#pragma unroll
  for (int i = 0; i < 2; i++) {
    int c = cc + i * 32;
    bf16x8 p;
#pragma unroll
    for (int j = 0; j < 8; j++) p[j] = *(const short*)&tile[rb * 8 + j][c];
    *(bf16x8*)(out + (size_t)(c0 + c) * R + r0 + rb * 8) = p;
  }
}

// ---------------- fused embedding gather + layernorm (row = blockIdx) ----------
__global__ void k_embln(const int* __restrict__ tok, const float* __restrict__ emb,
                        const float* __restrict__ g, const float* __restrict__ b,
                        float* __restrict__ h, bf16* __restrict__ ob,
                        float* __restrict__ of) {
  int row = blockIdx.x;
  int tid = threadIdx.x;
  int t = tok[row];
  float4 v = ((const float4*)(emb + (size_t)t * kD))[tid];
  ((float4*)(h + (size_t)row * kD))[tid] = v;  // raw embed (residual source)
  float sum = v.x + v.y + v.z + v.w;
  float sq = fmaf(v.x, v.x, fmaf(v.y, v.y, fmaf(v.z, v.z, v.w * v.w)));
#pragma unroll
  for (int o = 32; o > 0; o >>= 1) {
    sum += __shfl_down(sum, o);
    sq += __shfl_down(sq, o);
  }
  __shared__ float ss[4], sk[4];
  int w = tid >> 6;
  if ((tid & 63) == 0) { ss[w] = sum; sk[w] = sq; }
  __syncthreads();
  float ts = ss[0] + ss[1] + ss[2] + ss[3];
  float tq = sk[0] + sk[1] + sk[2] + sk[3];
  float mu = ts * (1.0f / kD);
  float var = tq * (1.0f / kD) - mu * mu;
  float rstd = rsqrtf(var + 1e-5f);
  float4 gg = ((const float4*)g)[tid];
  float4 bb = ((const float4*)b)[tid];
  float4 o;
  o.x = fmaf((v.x - mu) * rstd, gg.x, bb.x);
  o.y = fmaf((v.y - mu) * rstd, gg.y, bb.y);
  o.z = fmaf((v.z - mu) * rstd, gg.z, bb.z);
  o.w = fmaf((v.w - mu) * rstd, gg.w, bb.w);
  union { ushort4 u; bf16 hh[4]; } pk;
  pk.hh[0] = __float2bfloat16(o.x);
  pk.hh[1] = __float2bfloat16(o.y);
  pk.hh[2] = __float2bfloat16(o.z);
  pk.hh[3] = __float2bfloat16(o.w);
  *(ushort4*)(ob + (size_t)row * kD + tid * 4) = pk.u;
  ((float4*)(of + (size_t)row * kD))[tid] = o;
}

// ---------------- row layernorm (D=1024), 256 threads/row ----------------
template <bool WF32>
__global__ void k_ln(const float* __restrict__ in, const float* __restrict__ g,
                     const float* __restrict__ b, bf16* __restrict__ ob,
                     float* __restrict__ of) {
  int row = blockIdx.x;
  int tid = threadIdx.x;
  const float4* x4 = (const float4*)(in + (size_t)row * kD);
  float4 v = x4[tid];
  float sum = v.x + v.y + v.z + v.w;
  float sq = fmaf(v.x, v.x, fmaf(v.y, v.y, fmaf(v.z, v.z, v.w * v.w)));
#pragma unroll
  for (int o = 32; o > 0; o >>= 1) {
    sum += __shfl_down(sum, o);
    sq += __shfl_down(sq, o);
  }
  __shared__ float ss[4], sk[4];
  int w = tid >> 6;
  if ((tid & 63) == 0) { ss[w] = sum; sk[w] = sq; }
  __syncthreads();
  float ts = ss[0] + ss[1] + ss[2] + ss[3];
  float tq = sk[0] + sk[1] + sk[2] + sk[3];
  float mu = ts * (1.0f / kD);
  float var = tq * (1.0f / kD) - mu * mu;
  float rstd = rsqrtf(var + 1e-5f);
  float4 gg = ((const float4*)g)[tid];
  float4 bb = ((const float4*)b)[tid];
  float4 o;
  o.x = fmaf((v.x - mu) * rstd, gg.x, bb.x);
  o.y = fmaf((v.y - mu) * rstd, gg.y, bb.y);
  o.z = fmaf((v.z - mu) * rstd, gg.z, bb.z);
  o.w = fmaf((v.w - mu) * rstd, gg.w, bb.w);
  union { ushort4 u; bf16 h[4]; } pk;
  pk.h[0] = __float2bfloat16(o.x);
  pk.h[1] = __float2bfloat16(o.y);
  pk.h[2] = __float2bfloat16(o.z);
  pk.h[3] = __float2bfloat16(o.w);
  *(ushort4*)(ob + (size_t)row * kD + tid * 4) = pk.u;
  if constexpr (WF32) {
    ((float4*)(of + (size_t)row * kD))[tid] = o;
  }
}

// ---------------- phasor scan: pass A (chunk partial sums) ----------------
__global__ void k_scan_part(const float* __restrict__ v, const float* __restrict__ c,
                            const float* __restrict__ s, float* __restrict__ pr,
                            float* __restrict__ pi) {
  int tid = blockIdx.x * 256 + threadIdx.x;  // b*16384 + ch*1024 + d
  int d = tid & (kD - 1);
  int ch = (tid >> 10) & (kNC - 1);
  int b = tid >> 14;
  const float* vp = v + ((size_t)b * kL + ch * kCH) * kD + d;
  const float* cp = c + (size_t)(ch * kCH) * kD + d;
  const float* sp = s + (size_t)(ch * kCH) * kD + d;
  float ar = 0.f, ai = 0.f;
  for (int i = 0; i < kCH; i++) {
    float vv = vp[i * kD];
    ar = fmaf(vv, cp[i * kD], ar);
    ai = fmaf(vv, sp[i * kD], ai);
  }
  pr[tid] = ar;
  pi[tid] = ai;
}

// ---------------- phasor scan: pass B (apply, in-place over v) ----------------
__global__ void k_scan_apply(float* __restrict__ v, const float* __restrict__ c,
                             const float* __restrict__ s, const float* __restrict__ pr,
                             const float* __restrict__ pi) {
  int tid = blockIdx.x * 256 + threadIdx.x;
  int d = tid & (kD - 1);
  int ch = (tid >> 10) & (kNC - 1);
  int b = tid >> 14;
  float ar = 0.f, ai = 0.f;
  int pbase = (b << 14) + d;
  for (int cc = 0; cc < ch; cc++) {
    ar += pr[pbase + cc * kD];
    ai += pi[pbase + cc * kD];
  }
  float* vp = v + ((size_t)b * kL + ch * kCH) * kD + d;
  const float* cp = c + (size_t)(ch * kCH) * kD + d;
  const float* sp = s + (size_t)(ch * kCH) * kD + d;
  for (int i = 0; i < kCH; i++) {
    float vv = vp[i * kD];
    float cv = cp[i * kD], sv = sp[i * kD];
    ar = fmaf(vv, cv, ar);
    ai = fmaf(vv, sv, ai);
    vp[i * kD] = (ar * cv + ai * sv) * 0.03125f;  // 1/sqrt(1024)
  }
}

// ---------------- 128x128-tile GEMM (R0 config, proven) for small D x D ----
template <int MODE>
__global__ __launch_bounds__(256) void k_gemm_bt(
    const bf16* __restrict__ A, const bf16* __restrict__ BT,
    const float* __restrict__ bias, const float* __restrict__ xres,
    const float* __restrict__ hres, float* __restrict__ Cout,
    int Md, int Nd, int Kd) {
  __shared__ __align__(16) bf16 As[128 * 32];
  __shared__ __align__(16) bf16 Bs[128 * 32];
  int nwg = gridDim.x * gridDim.y;
  int wg = blockIdx.y * gridDim.x + blockIdx.x;
  int per = nwg >> 3;
  int sw = (wg & 7) * per + (wg >> 3);
  int bm = sw % gridDim.x;
  int bn = sw / gridDim.x;
  int m0 = bm * 128, n0 = bn * 128;
  int tid = threadIdx.x;
  int wid = tid >> 6, lane = tid & 63;
  int wr = wid >> 1, wc = wid & 1;

  f32x4 acc[4][4];
#pragma unroll
  for (int i = 0; i < 4; i++)
#pragma unroll
    for (int j = 0; j < 4; j++) acc[i][j] = (f32x4){0.f, 0.f, 0.f, 0.f};

  const bf16* Abase = A + (size_t)m0 * Kd;
  const bf16* Bbase = BT + (size_t)n0 * Kd;
  int lr = lane >> 2;
  int lk = (lane & 3) * 8;
  int frow = lane & 15;
  int fk = (lane >> 4) * 8;

  for (int k0 = 0; k0 < Kd; k0 += 32) {
#pragma unroll
    for (int c = 0; c < 2; c++) {
      int ch = wid + c * 4;
      __builtin_amdgcn_global_load_lds(GPTR(Abase + (size_t)(ch * 16 + lr) * Kd + k0 + lk),
                                       LPTR(As + ch * 512), 16, 0, 0);
      __builtin_amdgcn_global_load_lds(GPTR(Bbase + (size_t)(ch * 16 + lr) * Kd + k0 + lk),
                                       LPTR(Bs + ch * 512), 16, 0, 0);
    }
    asm volatile("s_waitcnt vmcnt(0)" ::: "memory");
    __syncthreads();
    bf16x8 af[4], bfr[4];
#pragma unroll
    for (int i = 0; i < 4; i++) {
      af[i] = *(const bf16x8*)(As + (wr * 64 + i * 16 + frow) * 32 + fk);
      bfr[i] = *(const bf16x8*)(Bs + (wc * 64 + i * 16 + frow) * 32 + fk);
    }
#pragma unroll
    for (int i = 0; i < 4; i++)
#pragma unroll
      for (int j = 0; j < 4; j++)
        acc[i][j] = __builtin_amdgcn_mfma_f32_16x16x32_bf16(af[i], bfr[j], acc[i][j], 0, 0, 0);
    __syncthreads();
  }

  int cr = (lane >> 4) * 4;
  int ccl = lane & 15;
#pragma unroll
  for (int i = 0; i < 4; i++) {
#pragma unroll
    for (int j = 0; j < 4; j++) {
      int col = n0 + wc * 64 + j * 16 + ccl;
      float bv = bias[col];
#pragma unroll
      for (int r = 0; r < 4; r++) {
        int row = m0 + wr * 64 + i * 16 + cr + r;
        size_t idx = (size_t)row * Nd + col;
        float val = acc[i][j][r] + bv;
        if (MODE == 1) val += hres[idx] + xres[idx];
        Cout[idx] = val;
      }
    }
  }
}

// ============================================================================
// 256x256 4-phase/K-tile head GEMM. R9 = R8 with the compile fix:
// __builtin_nontemporal_store requires a clang ext_vector pointer, not HIP's
// float4 class -> use f32x4. Theory unchanged from R8:
//  - R7 falsified "same-wave halves write-combine" (WRITE 1.27->1.40 GB):
//    nt bypasses L2 write-combining entirely; every 64B store instruction is
//    a partial-line transaction. Fix at instruction level: per-wave LDS
//    transpose (dead As buffer, disjoint per wave, no barriers) so each nt
//    store is a dwordx4 with contiguous lanes: 64 lanes x 16B = full aligned
//    128B lines only.
//  - Keep nt: (total - head) = 273/277 us on both nt rounds vs 334-354 on
//    all plain rounds (head's 1GB plain write flushes L3 -> next graph
//    iteration's leading kernels pay HBM re-reads).
// Falsifiable: WRITE_SIZE ~1.03e6 (else nt never coalesces -> revert nt);
// head ~710-730 us.
// ============================================================================
__global__ __launch_bounds__(512, 2) void k_gemm256p8(
    const bf16* __restrict__ A, const bf16* __restrict__ BT,
    const float* __restrict__ bias, float* __restrict__ Cout,
    int Md, int Nd, int Kd) {
  __shared__ __align__(16) bf16 As[2][16384];  // [buf][256 rows x 64 k]
  __shared__ __align__(16) bf16 Bs[2][16384];

  int gx = gridDim.x;
  int wg = blockIdx.y * gx + blockIdx.x;
  int mch = gx >> 3;                 // bm-chunk per XCD (gx % 8 == 0)
  int xcd = wg & 7;
  int r = wg >> 3;
  int bm = xcd * mch + (r % mch);
  int bn = r / mch;
  int m0 = bm * 256, n0 = bn * 256;

  int tid = threadIdx.x;
  int wid = tid >> 6, lane = tid & 63;
  int wr = wid >> 2, wc = wid & 3;  // A row m*32+wr*16; B col block wc*64 (contiguous)

  size_t KdS = (size_t)Kd;
  int srow = tid >> 3;                               // 0..63 slab row
  int sk = (((tid & 7) ^ (srow & 7)) << 3);          // source elem offset
  const bf16* aSrc = A + (size_t)(m0 + srow) * KdS + sk;
  const bf16* bSrc = BT + (size_t)(n0 + srow) * KdS + sk;
  int ldst = wid * 512;                              // wave-uniform elem base

#define STAGE_A(buf, h, t)                                                              \
  do {                                                                                  \
    __builtin_amdgcn_global_load_lds(GPTR(aSrc + (size_t)((h) * 128) * KdS + (t) * 64), \
                                     LPTR(&As[buf][(h) * 8192 + ldst]), 16, 0, 0);      \
    __builtin_amdgcn_global_load_lds(                                                   \
        GPTR(aSrc + (size_t)((h) * 128 + 64) * KdS + (t) * 64),                         \
        LPTR(&As[buf][(h) * 8192 + 4096 + ldst]), 16, 0, 0);                            \
  } while (0)
#define STAGE_B(buf, h, t)                                                              \
  do {                                                                                  \
    __builtin_amdgcn_global_load_lds(GPTR(bSrc + (size_t)((h) * 128) * KdS + (t) * 64), \
                                     LPTR(&Bs[buf][(h) * 8192 + ldst]), 16, 0, 0);      \
    __builtin_amdgcn_global_load_lds(                                                   \
        GPTR(bSrc + (size_t)((h) * 128 + 64) * KdS + (t) * 64),                         \
        LPTR(&Bs[buf][(h) * 8192 + 4096 + ldst]), 16, 0, 0);                            \
  } while (0)

  int frow = lane & 15;
  int khi = lane >> 4;   // 0..3
  int rx = frow & 7;
  int lk0 = ((khi) ^ rx) << 3;        // k-window 0 (k 0..31)
  int lk1 = ((4 + khi) ^ rx) << 3;    // k-window 1 (k 32..63)
  int wr16 = wr * 16;
  int wc64 = wc * 64;                 // contiguous 64-col block per wave

  f32x4 acc[8][4];
#pragma unroll
  for (int m = 0; m < 8; m++)
#pragma unroll
    for (int n = 0; n < 4; n++) acc[m][n] = (f32x4){0.f, 0.f, 0.f, 0.f};

  const int NT = Kd >> 6;  // 16 K-tiles of 64

  // ---- prologue: tile0 fully -> buf0 (A0,B0,B1,A1), tile1 A0,B0,B1 -> buf1
  STAGE_A(0, 0, 0);
  STAGE_B(0, 0, 0);
  STAGE_B(0, 1, 0);
  STAGE_A(0, 1, 0);
  STAGE_A(1, 0, 1);
  STAGE_B(1, 0, 1);
  STAGE_B(1, 1, 1);
  asm volatile("s_waitcnt vmcnt(6)" ::: "memory");  // tile0's 8 loads landed
  __builtin_amdgcn_s_barrier();
  __builtin_amdgcn_sched_barrier(0);

  for (int t = 0; t < NT; ++t) {
    int c = t & 1, o = c ^ 1;
    const bf16* Ac = As[c];
    const bf16* Bc = Bs[c];
    bf16x8 a[4][2], b[2][2], b2[2][2];

    // ===== phase 0: read a(m0..3) + b(n0..1); stage A-h1(t+1)->oth; MFMA
#pragma unroll
    for (int m = 0; m < 4; m++) {
      int ro = (m * 32 + wr16 + frow) * 64;
      a[m][0] = *(const bf16x8*)(Ac + ro + lk0);
      a[m][1] = *(const bf16x8*)(Ac + ro + lk1);
    }
#pragma unroll
    for (int n = 0; n < 2; n++) {
      int ro = (wc64 + n * 16 + frow) * 64;
      b[n][0] = *(const bf16x8*)(Bc + ro + lk0);
      b[n][1] = *(const bf16x8*)(Bc + ro + lk1);
    }
    if (t + 1 < NT) STAGE_A(o, 1, t + 1);
    __builtin_amdgcn_s_barrier();
    asm volatile("s_waitcnt lgkmcnt(0)" ::: "memory");
    __builtin_amdgcn_sched_barrier(0);
    __builtin_amdgcn_s_setprio(1);
#pragma unroll
    for (int m = 0; m < 4; m++)
#pragma unroll
      for (int n = 0; n < 2; n++) {
        acc[m][n] = __builtin_amdgcn_mfma_f32_16x16x32_bf16(a[m][0], b[n][0], acc[m][n], 0, 0, 0);
        acc[m][n] = __builtin_amdgcn_mfma_f32_16x16x32_bf16(a[m][1], b[n][1], acc[m][n], 0, 0, 0);
      }
    __builtin_amdgcn_s_setprio(0);
    __builtin_amdgcn_s_barrier();
    __builtin_amdgcn_sched_barrier(0);

    // ===== phase 1: read b2(n2..3); stage A-h0(t+2)->cur; MFMA
#pragma unroll
    for (int n = 0; n < 2; n++) {
      int ro = (wc64 + (n + 2) * 16 + frow) * 64;
      b2[n][0] = *(const bf16x8*)(Bc + ro + lk0);
      b2[n][1] = *(const bf16x8*)(Bc + ro + lk1);
    }
    if (t + 2 < NT) STAGE_A(c, 0, t + 2);
    __builtin_amdgcn_s_barrier();
    asm volatile("s_waitcnt lgkmcnt(0)" ::: "memory");
    __builtin_amdgcn_sched_barrier(0);
    __builtin_amdgcn_s_setprio(1);
#pragma unroll
    for (int m = 0; m < 4; m++)
#pragma unroll
      for (int n = 0; n < 2; n++) {
        acc[m][n + 2] = __builtin_amdgcn_mfma_f32_16x16x32_bf16(a[m][0], b2[n][0], acc[m][n + 2], 0, 0, 0);
        acc[m][n + 2] = __builtin_amdgcn_mfma_f32_16x16x32_bf16(a[m][1], b2[n][1], acc[m][n + 2], 0, 0, 0);
      }
    __builtin_amdgcn_s_setprio(0);
    __builtin_amdgcn_s_barrier();
    __builtin_amdgcn_sched_barrier(0);

    // ===== phase 2: read a(m4..7); stage B-h0(t+2)->cur; MFMA
#pragma unroll
    for (int m = 0; m < 4; m++) {
      int ro = ((m + 4) * 32 + wr16 + frow) * 64;
      a[m][0] = *(const bf16x8*)(Ac + ro + lk0);
      a[m][1] = *(const bf16x8*)(Ac + ro + lk1);
    }
    if (t + 2 < NT) STAGE_B(c, 0, t + 2);
    __builtin_amdgcn_s_barrier();
    asm volatile("s_waitcnt lgkmcnt(0)" ::: "memory");
    __builtin_amdgcn_sched_barrier(0);
    __builtin_amdgcn_s_setprio(1);
#pragma unroll
    for (int m = 0; m < 4; m++)
#pragma unroll
      for (int n = 0; n < 2; n++) {
        acc[m + 4][n] = __builtin_amdgcn_mfma_f32_16x16x32_bf16(a[m][0], b[n][0], acc[m + 4][n], 0, 0, 0);
        acc[m + 4][n] = __builtin_amdgcn_mfma_f32_16x16x32_bf16(a[m][1], b[n][1], acc[m + 4][n], 0, 0, 0);
      }
    __builtin_amdgcn_s_setprio(0);
    __builtin_amdgcn_s_barrier();
    __builtin_amdgcn_sched_barrier(0);

    // ===== phase 3: no reads; stage B-h1(t+2)->cur; MFMA; gate
    if (t + 2 < NT) STAGE_B(c, 1, t + 2);
    __builtin_amdgcn_s_barrier();
    __builtin_amdgcn_sched_barrier(0);
    __builtin_amdgcn_s_setprio(1);
#pragma unroll
    for (int m = 0; m < 4; m++)
#pragma unroll
      for (int n = 0; n < 2; n++) {
        acc[m + 4][n + 2] = __builtin_amdgcn_mfma_f32_16x16x32_bf16(a[m][0], b2[n][0], acc[m + 4][n + 2], 0, 0, 0);
        acc[m + 4][n + 2] = __builtin_amdgcn_mfma_f32_16x16x32_bf16(a[m][1], b2[n][1], acc[m + 4][n + 2], 0, 0, 0);
      }
    __builtin_amdgcn_s_setprio(0);
    if (t < NT - 2) {
      asm volatile("s_waitcnt vmcnt(6)" ::: "memory");  // 3 half-tiles in flight
    } else if (t == NT - 2) {
      asm volatile("s_waitcnt vmcnt(0)" ::: "memory");  // drain for last tile
    }
    __builtin_amdgcn_s_barrier();
    __builtin_amdgcn_sched_barrier(0);
  }
#undef STAGE_A
#undef STAGE_B

  // ---- epilogue: per-wave LDS transpose -> full-line nt dwordx4 stores ----
  // Per (wave, m): C-tile = 16 rows x 64 contiguous cols. Scatter to a
  // per-wave 16x68-padded f32 scratch in the dead As buffer (disjoint per
  // wave, no barriers; final K-loop barrier above guarantees all LDS reads
  // done), read back row-major f32x4/lane, store nt: 64 lanes x 16B =
  // 4 rows x 256B contiguous = full aligned 128B lines only.
  float* eplds = (float*)&As[0][0] + wid * 1088;  // 1088 f32 = 4352 B per wave
  int q = lane & 15;
  int g = lane >> 4;
  float bv[4];
#pragma unroll
  for (int n = 0; n < 4; n++) bv[n] = bias[n0 + wc64 + n * 16 + q];
#pragma unroll
  for (int m = 0; m < 8; m++) {
#pragma unroll
    for (int n = 0; n < 4; n++)
#pragma unroll
      for (int r2 = 0; r2 < 4; r2++)
        eplds[(g * 4 + r2) * 68 + n * 16 + q] = acc[m][n][r2] + bv[n];
    asm volatile("s_waitcnt lgkmcnt(0)" ::: "memory");
    __builtin_amdgcn_sched_barrier(0);
#pragma unroll
    for (int rr = 0; rr < 4; rr++) {
      f32x4 v4 = *(const f32x4*)(eplds + (rr * 4 + g) * 68 + q * 4);
      int row = m0 + m * 32 + wr16 + rr * 4 + g;
      __builtin_nontemporal_store(
          v4, (f32x4*)(Cout + (size_t)row * Nd + n0 + wc64 + q * 4));
    }
    asm volatile("s_waitcnt lgkmcnt(0)" ::: "memory");  // reads done before next m overwrites
    __builtin_amdgcn_sched_barrier(0);
  }
}

extern "C" void kernel_launch(void* const* d_in, const int* in_sizes, int n_in,
                              void* d_out, int out_size, void* d_ws, size_t ws_size,
                              hipStream_t stream) {
  const int* tokens   = (const int*)d_in[0];
  const float* embed  = (const float*)d_in[1];
  const float* ln1_g  = (const float*)d_in[2];
  const float* ln1_b  = (const float*)d_in[3];
  const float* ph1    = (const float*)d_in[4];
  const float* wv1    = (const float*)d_in[5];
  const float* bv1    = (const float*)d_in[6];
  const float* lno1_g = (const float*)d_in[7];
  const float* lno1_b = (const float*)d_in[8];
  const float* wo1    = (const float*)d_in[9];
  const float* bo1    = (const float*)d_in[10];
  const float* ln2_g  = (const float*)d_in[11];
  const float* ln2_b  = (const float*)d_in[12];
  const float* ph2    = (const float*)d_in[13];
  const float* wv2    = (const float*)d_in[14];
  const float* bv2    = (const float*)d_in[15];
  const float* lno2_g = (const float*)d_in[16];
  const float* lno2_b = (const float*)d_in[17];
  const float* wo2    = (const float*)d_in[18];
  const float* bo2    = (const float*)d_in[19];
  const float* ln3_g  = (const float*)d_in[20];
  const float* ln3_b  = (const float*)d_in[21];
  const float* w_head = (const float*)d_in[22];
  const float* b_head = (const float*)d_in[23];

  float* out = (float*)d_out;

  // ws: bf16 weights (transposed) + bf16 LN output  (~91 MB)
  char* ws = (char*)d_ws;
  bf16* whT  = (bf16*)ws;                    // [V][D]
  bf16* wv1T = whT + (size_t)kV * kD;        // [D][D] each
  bf16* wo1T = wv1T + (size_t)kD * kD;
  bf16* wv2T = wo1T + (size_t)kD * kD;
  bf16* wo2T = wv2T + (size_t)kD * kD;
  bf16* xb   = wo2T + (size_t)kD * kD;       // [M][D] bf16 (LN output, reused)

  // f32 activations live in d_out (1 GB); fully overwritten by the final GEMM
  float* h  = out;                            // [M][D]
  float* xf = h + (size_t)kM * kD;            // [M][D]
  float* vb = xf + (size_t)kM * kD;           // [M][D] v / retrieved (in-place)
  float* ct = vb + (size_t)kM * kD;           // [L][D]
  float* st = ct + (size_t)kL * kD;           // [L][D]
  float* pr = st + (size_t)kL * kD;           // [B][NC][D]
  float* pi = pr + (size_t)kB * kNC * kD;

  // weight conversion (transpose to [N][K] bf16), 64x64 vectorized tiles
  k_tcvt64<<<dim3(kD / 64, kD / 64), 256, 0, stream>>>(wv1, wv1T, kD, kD);
  k_tcvt64<<<dim3(kD / 64, kD / 64), 256, 0, stream>>>(wo1, wo1T, kD, kD);
  k_tcvt64<<<dim3(kD / 64, kD / 64), 256, 0, stream>>>(wv2, wv2T, kD, kD);
  k_tcvt64<<<dim3(kD / 64, kD / 64), 256, 0, stream>>>(wo2, wo2T, kD, kD);
  k_tcvt64<<<dim3(kV / 64, kD / 64), 256, 0, stream>>>(w_head, whT, kD, kV);

  const int scanBlocks = kB * kNC * kD / 256;  // 256

  // ---- phasor block 1 ----
  k_sincos<<<(kL * kD + 255) / 256, 256, 0, stream>>>(ph1, ct, st, kL * kD);
  k_embln<<<kM, 256, 0, stream>>>(tokens, embed, ln1_g, ln1_b, h, xb, xf);
  k_gemm_bt<0><<<dim3(kM / 128, kD / 128), 256, 0, stream>>>(xb, wv1T, bv1, nullptr, nullptr,
                                                             vb, kM, kD, kD);
  k_scan_part<<<scanBlocks, 256, 0, stream>>>(vb, ct, st, pr, pi);
  k_scan_apply<<<scanBlocks, 256, 0, stream>>>(vb, ct, st, pr, pi);
  k_ln<false><<<kM, 256, 0, stream>>>(vb, lno1_g, lno1_b, xb, nullptr);
  k_gemm_bt<1><<<dim3(kM / 128, kD / 128), 256, 0, stream>>>(xb, wo1T, bo1, xf, h,
                                                             h, kM, kD, kD);

  // ---- phasor block 2 ----
  k_sincos<<<(kL * kD + 255) / 256, 256, 0, stream>>>(ph2, ct, st, kL * kD);
  k_ln<true><<<kM, 256, 0, stream>>>(h, ln2_g, ln2_b, xb, xf);
  k_gemm_bt<0><<<dim3(kM / 128, kD / 128), 256, 0, stream>>>(xb, wv2T, bv2, nullptr, nullptr,
                                                             vb, kM, kD, kD);
  k_scan_part<<<scanBlocks, 256, 0, stream>>>(vb, ct, st, pr, pi);
  k_scan_apply<<<scanBlocks, 256, 0, stream>>>(vb, ct, st, pr, pi);
  k_ln<false><<<kM, 256, 0, stream>>>(vb, lno2_g, lno2_b, xb, nullptr);
  k_gemm_bt<1><<<dim3(kM / 128, kD / 128), 256, 0, stream>>>(xb, wo2T, bo2, xf, h,
                                                             h, kM, kD, kD);

  // ---- final LN + head GEMM (R7 K-loop + LDS-transposed full-line nt stores) ----
  k_ln<false><<<kM, 256, 0, stream>>>(h, ln3_g, ln3_b, xb, nullptr);
  k_gemm256p8<<<dim3(kM / 256, kV / 256), 512, 0, stream>>>(xb, whT, b_head, out,
                                                            kM, kV, kD);
}

// Round 10
// 930.340 us; speedup vs baseline: 1.2842x; 1.0343x over previous
//
#include <hip/hip_runtime.h>
#include <hip/hip_bf16.h>
#include <math.h>

typedef __hip_bfloat16 bf16;
typedef __attribute__((ext_vector_type(8))) short bf16x8;
typedef __attribute__((ext_vector_type(4))) float f32x4;

#define GPTR(p) ((__attribute__((address_space(1))) void*)(void*)(p))
#define LPTR(p) ((__attribute__((address_space(3))) void*)(void*)(p))

static constexpr int kB = 4, kL = 2048, kD = 1024, kV = 32000;
static constexpr int kM = kB * kL;                 // 8192
static constexpr int kNC = 16, kCH = kL / kNC;     // 16 chunks of 128

// ---------------- sincos tables ----------------
__global__ void k_sincos(const float* __restrict__ ph, float* __restrict__ c,
                         float* __restrict__ s, int n) {
  int i = blockIdx.x * 256 + threadIdx.x;
  if (i < n) {
    float sv, cv;
    sincosf(ph[i], &sv, &cv);
    c[i] = cv;
    s[i] = sv;
  }
}

// ---------------- transpose + f32 -> bf16 : in[R][C] -> out[C][R] ----------------
__global__ void k_tcvt64(const float* __restrict__ in, bf16* __restrict__ out,
                         int R, int C) {
  __shared__ bf16 tile[64][66];
  int c0 = blockIdx.x * 64, r0 = blockIdx.y * 64;
  int tid = threadIdx.x;  // 256
  int cq = tid & 15;
  int rr = tid >> 4;
#pragma unroll
  for (int i = 0; i < 4; i++) {
    int r = rr + i * 16;
    float4 v = *(const float4*)(in + (size_t)(r0 + r) * C + c0 + cq * 4);
    tile[r][cq * 4 + 0] = __float2bfloat16(v.x);
    tile[r][cq * 4 + 1] = __float2bfloat16(v.y);
    tile[r][cq * 4 + 2] = __float2bfloat16(v.z);
    tile[r][cq * 4 + 3] = __float2bfloat16(v.w);
  }
  __syncthreads();
  int rb = tid & 7;
  int cc = tid >> 3;
#pragma unroll
  for (int i = 0; i < 2; i++) {
    int c = cc + i * 32;
    bf16x8 p;
#pragma unroll
    for (int j = 0; j < 8; j++) p[j] = *(const short*)&tile[rb * 8 + j][c];
    *(bf16x8*)(out + (size_t)(c0 + c) * R + r0 + rb * 8) = p;
  }
}

// ---------------- fused embedding gather + layernorm (row = blockIdx) ----------
__global__ void k_embln(const int* __restrict__ tok, const float* __restrict__ emb,
                        const float* __restrict__ g, const float* __restrict__ b,
                        float* __restrict__ h, bf16* __restrict__ ob,
                        float* __restrict__ of) {
  int row = blockIdx.x;
  int tid = threadIdx.x;
  int t = tok[row];
  float4 v = ((const float4*)(emb + (size_t)t * kD))[tid];
  ((float4*)(h + (size_t)row * kD))[tid] = v;  // raw embed (residual source)
  float sum = v.x + v.y + v.z + v.w;
  float sq = fmaf(v.x, v.x, fmaf(v.y, v.y, fmaf(v.z, v.z, v.w * v.w)));
#pragma unroll
  for (int o = 32; o > 0; o >>= 1) {
    sum += __shfl_down(sum, o);
    sq += __shfl_down(sq, o);
  }
  __shared__ float ss[4], sk[4];
  int w = tid >> 6;
  if ((tid & 63) == 0) { ss[w] = sum; sk[w] = sq; }
  __syncthreads();
  float ts = ss[0] + ss[1] + ss[2] + ss[3];
  float tq = sk[0] + sk[1] + sk[2] + sk[3];
  float mu = ts * (1.0f / kD);
  float var = tq * (1.0f / kD) - mu * mu;
  float rstd = rsqrtf(var + 1e-5f);
  float4 gg = ((const float4*)g)[tid];
  float4 bb = ((const float4*)b)[tid];
  float4 o;
  o.x = fmaf((v.x - mu) * rstd, gg.x, bb.x);
  o.y = fmaf((v.y - mu) * rstd, gg.y, bb.y);
  o.z = fmaf((v.z - mu) * rstd, gg.z, bb.z);
  o.w = fmaf((v.w - mu) * rstd, gg.w, bb.w);
  union { ushort4 u; bf16 hh[4]; } pk;
  pk.hh[0] = __float2bfloat16(o.x);
  pk.hh[1] = __float2bfloat16(o.y);
  pk.hh[2] = __float2bfloat16(o.z);
  pk.hh[3] = __float2bfloat16(o.w);
  *(ushort4*)(ob + (size_t)row * kD + tid * 4) = pk.u;
  ((float4*)(of + (size_t)row * kD))[tid] = o;
}

// ---------------- row layernorm (D=1024), 256 threads/row ----------------
template <bool WF32>
__global__ void k_ln(const float* __restrict__ in, const float* __restrict__ g,
                     const float* __restrict__ b, bf16* __restrict__ ob,
                     float* __restrict__ of) {
  int row = blockIdx.x;
  int tid = threadIdx.x;
  const float4* x4 = (const float4*)(in + (size_t)row * kD);
  float4 v = x4[tid];
  float sum = v.x + v.y + v.z + v.w;
  float sq = fmaf(v.x, v.x, fmaf(v.y, v.y, fmaf(v.z, v.z, v.w * v.w)));
#pragma unroll
  for (int o = 32; o > 0; o >>= 1) {
    sum += __shfl_down(sum, o);
    sq += __shfl_down(sq, o);
  }
  __shared__ float ss[4], sk[4];
  int w = tid >> 6;
  if ((tid & 63) == 0) { ss[w] = sum; sk[w] = sq; }
  __syncthreads();
  float ts = ss[0] + ss[1] + ss[2] + ss[3];
  float tq = sk[0] + sk[1] + sk[2] + sk[3];
  float mu = ts * (1.0f / kD);
  float var = tq * (1.0f / kD) - mu * mu;
  float rstd = rsqrtf(var + 1e-5f);
  float4 gg = ((const float4*)g)[tid];
  float4 bb = ((const float4*)b)[tid];
  float4 o;
  o.x = fmaf((v.x - mu) * rstd, gg.x, bb.x);
  o.y = fmaf((v.y - mu) * rstd, gg.y, bb.y);
  o.z = fmaf((v.z - mu) * rstd, gg.z, bb.z);
  o.w = fmaf((v.w - mu) * rstd, gg.w, bb.w);
  union { ushort4 u; bf16 h[4]; } pk;
  pk.h[0] = __float2bfloat16(o.x);
  pk.h[1] = __float2bfloat16(o.y);
  pk.h[2] = __float2bfloat16(o.z);
  pk.h[3] = __float2bfloat16(o.w);
  *(ushort4*)(ob + (size_t)row * kD + tid * 4) = pk.u;
  if constexpr (WF32) {
    ((float4*)(of + (size_t)row * kD))[tid] = o;
  }
}

// ---------------- phasor scan: pass A (chunk partial sums) ----------------
__global__ void k_scan_part(const float* __restrict__ v, const float* __restrict__ c,
                            const float* __restrict__ s, float* __restrict__ pr,
                            float* __restrict__ pi) {
  int tid = blockIdx.x * 256 + threadIdx.x;  // b*16384 + ch*1024 + d
  int d = tid & (kD - 1);
  int ch = (tid >> 10) & (kNC - 1);
  int b = tid >> 14;
  const float* vp = v + ((size_t)b * kL + ch * kCH) * kD + d;
  const float* cp = c + (size_t)(ch * kCH) * kD + d;
  const float* sp = s + (size_t)(ch * kCH) * kD + d;
  float ar = 0.f, ai = 0.f;
  for (int i = 0; i < kCH; i++) {
    float vv = vp[i * kD];
    ar = fmaf(vv, cp[i * kD], ar);
    ai = fmaf(vv, sp[i * kD], ai);
  }
  pr[tid] = ar;
  pi[tid] = ai;
}

// ---------------- phasor scan: pass B (apply, in-place over v) ----------------
__global__ void k_scan_apply(float* __restrict__ v, const float* __restrict__ c,
                             const float* __restrict__ s, const float* __restrict__ pr,
                             const float* __restrict__ pi) {
  int tid = blockIdx.x * 256 + threadIdx.x;
  int d = tid & (kD - 1);
  int ch = (tid >> 10) & (kNC - 1);
  int b = tid >> 14;
  float ar = 0.f, ai = 0.f;
  int pbase = (b << 14) + d;
  for (int cc = 0; cc < ch; cc++) {
    ar += pr[pbase + cc * kD];
    ai += pi[pbase + cc * kD];
  }
  float* vp = v + ((size_t)b * kL + ch * kCH) * kD + d;
  const float* cp = c + (size_t)(ch * kCH) * kD + d;
  const float* sp = s + (size_t)(ch * kCH) * kD + d;
  for (int i = 0; i < kCH; i++) {
    float vv = vp[i * kD];
    float cv = cp[i * kD], sv = sp[i * kD];
    ar = fmaf(vv, cv, ar);
    ai = fmaf(vv, sv, ai);
    vp[i * kD] = (ar * cv + ai * sv) * 0.03125f;  // 1/sqrt(1024)
  }
}

// ============================================================================
// 128x256-tile D x D GEMM — R10: port of the PROVEN head template (4-phase
// collapses to 2 since A is consumed entirely in phase 0). Same XOR-swizzled
// LDS (zero K-loop bank conflicts), counted vmcnt gates, setprio, XCD map.
// Replaces the old 128^2/BK32/vmcnt(0)-per-step kernel (~400 TF, 8-way LDS
// conflicts, no pipeline). Grid 64x4 = 256 blocks = exactly 1/CU, 1 round.
// Stage schedule: ph0: B(t+1)->other buf [4] (B(o) consumed in prior tile's
// ph1, barrier between); ph1: A(t+2)->cur buf [2] (A(c) fully consumed in
// ph0, barrier between). Gate vmcnt(2) leaves only A(t+2) in flight ->
// A(t+1) and B(t+1) landed before next tile's ph0 reads them.
// Prologue: A(0),B(0),A(1) then vmcnt(2).
// ============================================================================
template <int MODE>
__global__ __launch_bounds__(512, 2) void k_gemm_bt2(
    const bf16* __restrict__ A, const bf16* __restrict__ BT,
    const float* __restrict__ bias, const float* __restrict__ xres,
    const float* __restrict__ hres, float* __restrict__ Cout,
    int Md, int Nd, int Kd) {
  __shared__ __align__(16) bf16 As[2][8192];   // [buf][128 rows x 64 k]
  __shared__ __align__(16) bf16 Bs[2][16384];  // [buf][256 rows x 64 k]

  int gx = gridDim.x;                 // 64
  int wg = blockIdx.y * gx + blockIdx.x;
  int mch = gx >> 3;                  // 8
  int xcd = wg & 7;
  int r = wg >> 3;
  int bm = xcd * mch + (r % mch);
  int bn = r / mch;
  int m0 = bm * 128, n0 = bn * 256;

  int tid = threadIdx.x;
  int wid = tid >> 6, lane = tid & 63;
  int wr = wid >> 2, wc = wid & 3;    // wave tile: 64 rows (wr) x 64 cols (wc)

  size_t KdS = (size_t)Kd;
  int srow = tid >> 3;                               // 0..63
  int sk = (((tid & 7) ^ (srow & 7)) << 3);
  const bf16* aSrc = A + (size_t)(m0 + srow) * KdS + sk;
  const bf16* bSrc = BT + (size_t)(n0 + srow) * KdS + sk;
  int ldst = wid * 512;

#define STAGE_A2(buf, t)                                                                \
  do {                                                                                  \
    __builtin_amdgcn_global_load_lds(GPTR(aSrc + (size_t)(t) * 64),                     \
                                     LPTR(&As[buf][ldst]), 16, 0, 0);                   \
    __builtin_amdgcn_global_load_lds(GPTR(aSrc + (size_t)64 * KdS + (size_t)(t) * 64),  \
                                     LPTR(&As[buf][4096 + ldst]), 16, 0, 0);            \
  } while (0)
#define STAGE_B2(buf, h, t)                                                             \
  do {                                                                                  \
    __builtin_amdgcn_global_load_lds(GPTR(bSrc + (size_t)((h) * 128) * KdS + (t) * 64), \
                                     LPTR(&Bs[buf][(h) * 8192 + ldst]), 16, 0, 0);      \
    __builtin_amdgcn_global_load_lds(                                                   \
        GPTR(bSrc + (size_t)((h) * 128 + 64) * KdS + (t) * 64),                         \
        LPTR(&Bs[buf][(h) * 8192 + 4096 + ldst]), 16, 0, 0);                            \
  } while (0)

  int frow = lane & 15;
  int khi = lane >> 4;
  int rx = frow & 7;
  int lk0 = ((khi) ^ rx) << 3;        // k 0..31 (after source swizzle)
  int lk1 = ((4 + khi) ^ rx) << 3;    // k 32..63
  int wr16 = wr * 16;
  int wc64 = wc * 64;

  f32x4 acc[4][4];
#pragma unroll
  for (int i = 0; i < 4; i++)
#pragma unroll
    for (int j = 0; j < 4; j++) acc[i][j] = (f32x4){0.f, 0.f, 0.f, 0.f};

  const int NT = Kd >> 6;  // 16

  // ---- prologue: A(0),B(0) -> buf0; A(1) -> buf1; wait all but A(1)
  STAGE_A2(0, 0);
  STAGE_B2(0, 0, 0);
  STAGE_B2(0, 1, 0);
  STAGE_A2(1, 1);
  asm volatile("s_waitcnt vmcnt(2)" ::: "memory");
  __builtin_amdgcn_s_barrier();
  __builtin_amdgcn_sched_barrier(0);

  for (int t = 0; t < NT; ++t) {
    int c = t & 1, o = c ^ 1;
    const bf16* Ac = As[c];
    const bf16* Bc = Bs[c];
    bf16x8 a[4][2], b[2][2], b2[2][2];

    // ===== phase 0: read all a + b(n0..1); stage B(t+1)->o; MFMA m0..3 x n0..1
#pragma unroll
    for (int m = 0; m < 4; m++) {
      int ro = (m * 32 + wr16 + frow) * 64;
      a[m][0] = *(const bf16x8*)(Ac + ro + lk0);
      a[m][1] = *(const bf16x8*)(Ac + ro + lk1);
    }
#pragma unroll
    for (int n = 0; n < 2; n++) {
      int ro = (wc64 + n * 16 + frow) * 64;
      b[n][0] = *(const bf16x8*)(Bc + ro + lk0);
      b[n][1] = *(const bf16x8*)(Bc + ro + lk1);
    }
    if (t + 1 < NT) {
      STAGE_B2(o, 0, t + 1);
      STAGE_B2(o, 1, t + 1);
    }
    __builtin_amdgcn_s_barrier();
    asm volatile("s_waitcnt lgkmcnt(0)" ::: "memory");
    __builtin_amdgcn_sched_barrier(0);
    __builtin_amdgcn_s_setprio(1);
#pragma unroll
    for (int m = 0; m < 4; m++)
#pragma unroll
      for (int n = 0; n < 2; n++) {
        acc[m][n] = __builtin_amdgcn_mfma_f32_16x16x32_bf16(a[m][0], b[n][0], acc[m][n], 0, 0, 0);
        acc[m][n] = __builtin_amdgcn_mfma_f32_16x16x32_bf16(a[m][1], b[n][1], acc[m][n], 0, 0, 0);
      }
    __builtin_amdgcn_s_setprio(0);
    __builtin_amdgcn_s_barrier();
    __builtin_amdgcn_sched_barrier(0);

    // ===== phase 1: read b2(n2..3); stage A(t+2)->c; MFMA m0..3 x n2..3; gate
#pragma unroll
    for (int n = 0; n < 2; n++) {
      int ro = (wc64 + (n + 2) * 16 + frow) * 64;
      b2[n][0] = *(const bf16x8*)(Bc + ro + lk0);
      b2[n][1] = *(const bf16x8*)(Bc + ro + lk1);
    }
    if (t + 2 < NT) STAGE_A2(c, t + 2);
    __builtin_amdgcn_s_barrier();
    asm volatile("s_waitcnt lgkmcnt(0)" ::: "memory");
    __builtin_amdgcn_sched_barrier(0);
    __builtin_amdgcn_s_setprio(1);
#pragma unroll
    for (int m = 0; m < 4; m++)
#pragma unroll
      for (int n = 0; n < 2; n++) {
        acc[m][n + 2] = __builtin_amdgcn_mfma_f32_16x16x32_bf16(a[m][0], b2[n][0], acc[m][n + 2], 0, 0, 0);
        acc[m][n + 2] = __builtin_amdgcn_mfma_f32_16x16x32_bf16(a[m][1], b2[n][1], acc[m][n + 2], 0, 0, 0);
      }
    __builtin_amdgcn_s_setprio(0);
    if (t < NT - 2) {
      asm volatile("s_waitcnt vmcnt(2)" ::: "memory");  // only A(t+2) in flight
    } else if (t == NT - 2) {
      asm volatile("s_waitcnt vmcnt(0)" ::: "memory");  // drain for last tile
    }
    __builtin_amdgcn_s_barrier();
    __builtin_amdgcn_sched_barrier(0);
  }
#undef STAGE_A2
#undef STAGE_B2

  // ---- epilogue: plain stores (outputs re-read by later kernels) ----
  int cr = (lane >> 4) * 4;
  int ccl = lane & 15;
#pragma unroll
  for (int m = 0; m < 4; m++) {
#pragma unroll
    for (int n = 0; n < 4; n++) {
      int col = n0 + wc64 + n * 16 + ccl;
      float bv = bias[col];
#pragma unroll
      for (int r2 = 0; r2 < 4; r2++) {
        int row = m0 + m * 32 + wr16 + cr + r2;
        size_t idx = (size_t)row * Nd + col;
        float val = acc[m][n][r2] + bv;
        if (MODE == 1) val += hres[idx] + xres[idx];
        Cout[idx] = val;
      }
    }
  }
}

// ============================================================================
// 256x256 4-phase/K-tile head GEMM (R9-proven: 691 us / 777 TF).
// wc64 contiguous-col waves; full-line nt epilogue via per-wave LDS
// transpose (WRITE confirmed 1.03e6; nt preserves L3 for the next graph
// iteration: total-head = 271-277 us vs 334-354 with plain stores).
// DO NOT MODIFY without within-session A/B.
// ============================================================================
__global__ __launch_bounds__(512, 2) void k_gemm256p8(
    const bf16* __restrict__ A, const bf16* __restrict__ BT,
    const float* __restrict__ bias, float* __restrict__ Cout,
    int Md, int Nd, int Kd) {
  __shared__ __align__(16) bf16 As[2][16384];  // [buf][256 rows x 64 k]
  __shared__ __align__(16) bf16 Bs[2][16384];

  int gx = gridDim.x;
  int wg = blockIdx.y * gx + blockIdx.x;
  int mch = gx >> 3;                 // bm-chunk per XCD (gx % 8 == 0)
  int xcd = wg & 7;
  int r = wg >> 3;
  int bm = xcd * mch + (r % mch);
  int bn = r / mch;
  int m0 = bm * 256, n0 = bn * 256;

  int tid = threadIdx.x;
  int wid = tid >> 6, lane = tid & 63;
  int wr = wid >> 2, wc = wid & 3;  // A row m*32+wr*16; B col block wc*64 (contiguous)

  size_t KdS = (size_t)Kd;
  int srow = tid >> 3;                               // 0..63 slab row
  int sk = (((tid & 7) ^ (srow & 7)) << 3);          // source elem offset
  const bf16* aSrc = A + (size_t)(m0 + srow) * KdS + sk;
  const bf16* bSrc = BT + (size_t)(n0 + srow) * KdS + sk;
  int ldst = wid * 512;                              // wave-uniform elem base

#define STAGE_A(buf, h, t)                                                              \
  do {                                                                                  \
    __builtin_amdgcn_global_load_lds(GPTR(aSrc + (size_t)((h) * 128) * KdS + (t) * 64), \
                                     LPTR(&As[buf][(h) * 8192 + ldst]), 16, 0, 0);      \
    __builtin_amdgcn_global_load_lds(                                                   \
        GPTR(aSrc + (size_t)((h) * 128 + 64) * KdS + (t) * 64),                         \
        LPTR(&As[buf][(h) * 8192 + 4096 + ldst]), 16, 0, 0);                            \
  } while (0)
#define STAGE_B(buf, h, t)                                                              \
  do {                                                                                  \
    __builtin_amdgcn_global_load_lds(GPTR(bSrc + (size_t)((h) * 128) * KdS + (t) * 64), \
                                     LPTR(&Bs[buf][(h) * 8192 + ldst]), 16, 0, 0);      \
    __builtin_amdgcn_global_load_lds(                                                   \
        GPTR(bSrc + (size_t)((h) * 128 + 64) * KdS + (t) * 64),                         \
        LPTR(&Bs[buf][(h) * 8192 + 4096 + ldst]), 16, 0, 0);                            \
  } while (0)

  int frow = lane & 15;
  int khi = lane >> 4;   // 0..3
  int rx = frow & 7;
  int lk0 = ((khi) ^ rx) << 3;        // k-window 0 (k 0..31)
  int lk1 = ((4 + khi) ^ rx) << 3;    // k-window 1 (k 32..63)
  int wr16 = wr * 16;
  int wc64 = wc * 64;                 // contiguous 64-col block per wave

  f32x4 acc[8][4];
#pragma unroll
  for (int m = 0; m < 8; m++)
#pragma unroll
    for (int n = 0; n < 4; n++) acc[m][n] = (f32x4){0.f, 0.f, 0.f, 0.f};

  const int NT = Kd >> 6;  // 16 K-tiles of 64

  // ---- prologue: tile0 fully -> buf0 (A0,B0,B1,A1), tile1 A0,B0,B1 -> buf1
  STAGE_A(0, 0, 0);
  STAGE_B(0, 0, 0);
  STAGE_B(0, 1, 0);
  STAGE_A(0, 1, 0);
  STAGE_A(1, 0, 1);
  STAGE_B(1, 0, 1);
  STAGE_B(1, 1, 1);
  asm volatile("s_waitcnt vmcnt(6)" ::: "memory");  // tile0's 8 loads landed
  __builtin_amdgcn_s_barrier();
  __builtin_amdgcn_sched_barrier(0);

  for (int t = 0; t < NT; ++t) {
    int c = t & 1, o = c ^ 1;
    const bf16* Ac = As[c];
    const bf16* Bc = Bs[c];
    bf16x8 a[4][2], b[2][2], b2[2][2];

    // ===== phase 0: read a(m0..3) + b(n0..1); stage A-h1(t+1)->oth; MFMA
#pragma unroll
    for (int m = 0; m < 4; m++) {
      int ro = (m * 32 + wr16 + frow) * 64;
      a[m][0] = *(const bf16x8*)(Ac + ro + lk0);
      a[m][1] = *(const bf16x8*)(Ac + ro + lk1);
    }
#pragma unroll
    for (int n = 0; n < 2; n++) {
      int ro = (wc64 + n * 16 + frow) * 64;
      b[n][0] = *(const bf16x8*)(Bc + ro + lk0);
      b[n][1] = *(const bf16x8*)(Bc + ro + lk1);
    }
    if (t + 1 < NT) STAGE_A(o, 1, t + 1);
    __builtin_amdgcn_s_barrier();
    asm volatile("s_waitcnt lgkmcnt(0)" ::: "memory");
    __builtin_amdgcn_sched_barrier(0);
    __builtin_amdgcn_s_setprio(1);
#pragma unroll
    for (int m = 0; m < 4; m++)
#pragma unroll
      for (int n = 0; n < 2; n++) {
        acc[m][n] = __builtin_amdgcn_mfma_f32_16x16x32_bf16(a[m][0], b[n][0], acc[m][n], 0, 0, 0);
        acc[m][n] = __builtin_amdgcn_mfma_f32_16x16x32_bf16(a[m][1], b[n][1], acc[m][n], 0, 0, 0);
      }
    __builtin_amdgcn_s_setprio(0);
    __builtin_amdgcn_s_barrier();
    __builtin_amdgcn_sched_barrier(0);

    // ===== phase 1: read b2(n2..3); stage A-h0(t+2)->cur; MFMA
#pragma unroll
    for (int n = 0; n < 2; n++) {
      int ro = (wc64 + (n + 2) * 16 + frow) * 64;
      b2[n][0] = *(const bf16x8*)(Bc + ro + lk0);
      b2[n][1] = *(const bf16x8*)(Bc + ro + lk1);
    }
    if (t + 2 < NT) STAGE_A(c, 0, t + 2);
    __builtin_amdgcn_s_barrier();
    asm volatile("s_waitcnt lgkmcnt(0)" ::: "memory");
    __builtin_amdgcn_sched_barrier(0);
    __builtin_amdgcn_s_setprio(1);
#pragma unroll
    for (int m = 0; m < 4; m++)
#pragma unroll
      for (int n = 0; n < 2; n++) {
        acc[m][n + 2] = __builtin_amdgcn_mfma_f32_16x16x32_bf16(a[m][0], b2[n][0], acc[m][n + 2], 0, 0, 0);
        acc[m][n + 2] = __builtin_amdgcn_mfma_f32_16x16x32_bf16(a[m][1], b2[n][1], acc[m][n + 2], 0, 0, 0);
      }
    __builtin_amdgcn_s_setprio(0);
    __builtin_amdgcn_s_barrier();
    __builtin_amdgcn_sched_barrier(0);

    // ===== phase 2: read a(m4..7); stage B-h0(t+2)->cur; MFMA
#pragma unroll
    for (int m = 0; m < 4; m++) {
      int ro = ((m + 4) * 32 + wr16 + frow) * 64;
      a[m][0] = *(const bf16x8*)(Ac + ro + lk0);
      a[m][1] = *(const bf16x8*)(Ac + ro + lk1);
    }
    if (t + 2 < NT) STAGE_B(c, 0, t + 2);
    __builtin_amdgcn_s_barrier();
    asm volatile("s_waitcnt lgkmcnt(0)" ::: "memory");
    __builtin_amdgcn_sched_barrier(0);
    __builtin_amdgcn_s_setprio(1);
#pragma unroll
    for (int m = 0; m < 4; m++)
#pragma unroll
      for (int n = 0; n < 2; n++) {
        acc[m + 4][n] = __builtin_amdgcn_mfma_f32_16x16x32_bf16(a[m][0], b[n][0], acc[m + 4][n], 0, 0, 0);
        acc[m + 4][n] = __builtin_amdgcn_mfma_f32_16x16x32_bf16(a[m][1], b[n][1], acc[m + 4][n], 0, 0, 0);
      }
    __builtin_amdgcn_s_setprio(0);
    __builtin_amdgcn_s_barrier();
    __builtin_amdgcn_sched_barrier(0);

    // ===== phase 3: no reads; stage B-h1(t+2)->cur; MFMA; gate
    if (t + 2 < NT) STAGE_B(c, 1, t + 2);
    __builtin_amdgcn_s_barrier();
    __builtin_amdgcn_sched_barrier(0);
    __builtin_amdgcn_s_setprio(1);
#pragma unroll
    for (int m = 0; m < 4; m++)
#pragma unroll
      for (int n = 0; n < 2; n++) {
        acc[m + 4][n + 2] = __builtin_amdgcn_mfma_f32_16x16x32_bf16(a[m][0], b2[n][0], acc[m + 4][n + 2], 0, 0, 0);
        acc[m + 4][n + 2] = __builtin_amdgcn_mfma_f32_16x16x32_bf16(a[m][1], b2[n][1], acc[m + 4][n + 2], 0, 0, 0);
      }
    __builtin_amdgcn_s_setprio(0);
    if (t < NT - 2) {
      asm volatile("s_waitcnt vmcnt(6)" ::: "memory");  // 3 half-tiles in flight
    } else if (t == NT - 2) {
      asm volatile("s_waitcnt vmcnt(0)" ::: "memory");  // drain for last tile
    }
    __builtin_amdgcn_s_barrier();
    __builtin_amdgcn_sched_barrier(0);
  }
#undef STAGE_A
#undef STAGE_B

  // ---- epilogue: per-wave LDS transpose -> full-line nt dwordx4 stores ----
  float* eplds = (float*)&As[0][0] + wid * 1088;  // 1088 f32 = 4352 B per wave
  int q = lane & 15;
  int g = lane >> 4;
  float bv[4];
#pragma unroll
  for (int n = 0; n < 4; n++) bv[n] = bias[n0 + wc64 + n * 16 + q];
#pragma unroll
  for (int m = 0; m < 8; m++) {
#pragma unroll
    for (int n = 0; n < 4; n++)
#pragma unroll
      for (int r2 = 0; r2 < 4; r2++)
        eplds[(g * 4 + r2) * 68 + n * 16 + q] = acc[m][n][r2] + bv[n];
    asm volatile("s_waitcnt lgkmcnt(0)" ::: "memory");
    __builtin_amdgcn_sched_barrier(0);
#pragma unroll
    for (int rr = 0; rr < 4; rr++) {
      f32x4 v4 = *(const f32x4*)(eplds + (rr * 4 + g) * 68 + q * 4);
      int row = m0 + m * 32 + wr16 + rr * 4 + g;
      __builtin_nontemporal_store(
          v4, (f32x4*)(Cout + (size_t)row * Nd + n0 + wc64 + q * 4));
    }
    asm volatile("s_waitcnt lgkmcnt(0)" ::: "memory");  // reads done before next m overwrites
    __builtin_amdgcn_sched_barrier(0);
  }
}

extern "C" void kernel_launch(void* const* d_in, const int* in_sizes, int n_in,
                              void* d_out, int out_size, void* d_ws, size_t ws_size,
                              hipStream_t stream) {
  const int* tokens   = (const int*)d_in[0];
  const float* embed  = (const float*)d_in[1];
  const float* ln1_g  = (const float*)d_in[2];
  const float* ln1_b  = (const float*)d_in[3];
  const float* ph1    = (const float*)d_in[4];
  const float* wv1    = (const float*)d_in[5];
  const float* bv1    = (const float*)d_in[6];
  const float* lno1_g = (const float*)d_in[7];
  const float* lno1_b = (const float*)d_in[8];
  const float* wo1    = (const float*)d_in[9];
  const float* bo1    = (const float*)d_in[10];
  const float* ln2_g  = (const float*)d_in[11];
  const float* ln2_b  = (const float*)d_in[12];
  const float* ph2    = (const float*)d_in[13];
  const float* wv2    = (const float*)d_in[14];
  const float* bv2    = (const float*)d_in[15];
  const float* lno2_g = (const float*)d_in[16];
  const float* lno2_b = (const float*)d_in[17];
  const float* wo2    = (const float*)d_in[18];
  const float* bo2    = (const float*)d_in[19];
  const float* ln3_g  = (const float*)d_in[20];
  const float* ln3_b  = (const float*)d_in[21];
  const float* w_head = (const float*)d_in[22];
  const float* b_head = (const float*)d_in[23];

  float* out = (float*)d_out;

  // ws: bf16 weights (transposed) + bf16 LN output  (~91 MB)
  char* ws = (char*)d_ws;
  bf16* whT  = (bf16*)ws;                    // [V][D]
  bf16* wv1T = whT + (size_t)kV * kD;        // [D][D] each
  bf16* wo1T = wv1T + (size_t)kD * kD;
  bf16* wv2T = wo1T + (size_t)kD * kD;
  bf16* wo2T = wv2T + (size_t)kD * kD;
  bf16* xb   = wo2T + (size_t)kD * kD;       // [M][D] bf16 (LN output, reused)

  // f32 activations live in d_out (1 GB); fully overwritten by the final GEMM
  float* h  = out;                            // [M][D]
  float* xf = h + (size_t)kM * kD;            // [M][D]
  float* vb = xf + (size_t)kM * kD;           // [M][D] v / retrieved (in-place)
  float* ct = vb + (size_t)kM * kD;           // [L][D]
  float* st = ct + (size_t)kL * kD;           // [L][D]
  float* pr = st + (size_t)kL * kD;           // [B][NC][D]
  float* pi = pr + (size_t)kB * kNC * kD;

  // weight conversion (transpose to [N][K] bf16), 64x64 vectorized tiles
  k_tcvt64<<<dim3(kD / 64, kD / 64), 256, 0, stream>>>(wv1, wv1T, kD, kD);
  k_tcvt64<<<dim3(kD / 64, kD / 64), 256, 0, stream>>>(wo1, wo1T, kD, kD);
  k_tcvt64<<<dim3(kD / 64, kD / 64), 256, 0, stream>>>(wv2, wv2T, kD, kD);
  k_tcvt64<<<dim3(kD / 64, kD / 64), 256, 0, stream>>>(wo2, wo2T, kD, kD);
  k_tcvt64<<<dim3(kV / 64, kD / 64), 256, 0, stream>>>(w_head, whT, kD, kV);

  const int scanBlocks = kB * kNC * kD / 256;  // 256

  // ---- phasor block 1 ----
  k_sincos<<<(kL * kD + 255) / 256, 256, 0, stream>>>(ph1, ct, st, kL * kD);
  k_embln<<<kM, 256, 0, stream>>>(tokens, embed, ln1_g, ln1_b, h, xb, xf);
  k_gemm_bt2<0><<<dim3(kM / 128, kD / 256), 512, 0, stream>>>(xb, wv1T, bv1, nullptr, nullptr,
                                                              vb, kM, kD, kD);
  k_scan_part<<<scanBlocks, 256, 0, stream>>>(vb, ct, st, pr, pi);
  k_scan_apply<<<scanBlocks, 256, 0, stream>>>(vb, ct, st, pr, pi);
  k_ln<false><<<kM, 256, 0, stream>>>(vb, lno1_g, lno1_b, xb, nullptr);
  k_gemm_bt2<1><<<dim3(kM / 128, kD / 256), 512, 0, stream>>>(xb, wo1T, bo1, xf, h,
                                                              h, kM, kD, kD);

  // ---- phasor block 2 ----
  k_sincos<<<(kL * kD + 255) / 256, 256, 0, stream>>>(ph2, ct, st, kL * kD);
  k_ln<true><<<kM, 256, 0, stream>>>(h, ln2_g, ln2_b, xb, xf);
  k_gemm_bt2<0><<<dim3(kM / 128, kD / 256), 512, 0, stream>>>(xb, wv2T, bv2, nullptr, nullptr,
                                                              vb, kM, kD, kD);
  k_scan_part<<<scanBlocks, 256, 0, stream>>>(vb, ct, st, pr, pi);
  k_scan_apply<<<scanBlocks, 256, 0, stream>>>(vb, ct, st, pr, pi);
  k_ln<false><<<kM, 256, 0, stream>>>(vb, lno2_g, lno2_b, xb, nullptr);
  k_gemm_bt2<1><<<dim3(kM / 128, kD / 256), 512, 0, stream>>>(xb, wo2T, bo2, xf, h,
                                                              h, kM, kD, kD);

  // ---- final LN + head GEMM (R9-proven: 4-phase + full-line nt epilogue) ----
  k_ln<false><<<kM, 256, 0, stream>>>(h, ln3_g, ln3_b, xb, nullptr);
  k_gemm256p8<<<dim3(kM / 256, kV / 256), 512, 0, stream>>>(xb, whT, b_head, out,
                                                            kM, kV, kD);
}

// Round 11
// 912.352 us; speedup vs baseline: 1.3095x; 1.0197x over previous
//
#include <hip/hip_runtime.h>
#include <hip/hip_bf16.h>
#include <math.h>

typedef __hip_bfloat16 bf16;
typedef __attribute__((ext_vector_type(8))) short bf16x8;
typedef __attribute__((ext_vector_type(4))) float f32x4;

#define GPTR(p) ((__attribute__((address_space(1))) void*)(void*)(p))
#define LPTR(p) ((__attribute__((address_space(3))) void*)(void*)(p))

static constexpr int kB = 4, kL = 2048, kD = 1024, kV = 32000;
static constexpr int kM = kB * kL;                 // 8192
static constexpr int kNC = 16, kCH = kL / kNC;     // 16 chunks of 128

// ---------------- sincos tables ----------------
__global__ void k_sincos(const float* __restrict__ ph, float* __restrict__ c,
                         float* __restrict__ s, int n) {
  int i = blockIdx.x * 256 + threadIdx.x;
  if (i < n) {
    float sv, cv;
    sincosf(ph[i], &sv, &cv);
    c[i] = cv;
    s[i] = sv;
  }
}

// ---------------- transpose + f32 -> bf16 : in[R][C] -> out[C][R] ----------------
__global__ void k_tcvt64(const float* __restrict__ in, bf16* __restrict__ out,
                         int R, int C) {
  __shared__ bf16 tile[64][66];
  int c0 = blockIdx.x * 64, r0 = blockIdx.y * 64;
  int tid = threadIdx.x;  // 256
  int cq = tid & 15;
  int rr = tid >> 4;
#pragma unroll
  for (int i = 0; i < 4; i++) {
    int r = rr + i * 16;
    float4 v = *(const float4*)(in + (size_t)(r0 + r) * C + c0 + cq * 4);
    tile[r][cq * 4 + 0] = __float2bfloat16(v.x);
    tile[r][cq * 4 + 1] = __float2bfloat16(v.y);
    tile[r][cq * 4 + 2] = __float2bfloat16(v.z);
    tile[r][cq * 4 + 3] = __float2bfloat16(v.w);
  }
  __syncthreads();
  int rb = tid & 7;
  int cc = tid >> 3;
#pragma unroll
  for (int i = 0; i < 2; i++) {
    int c = cc + i * 32;
    bf16x8 p;
#pragma unroll
    for (int j = 0; j < 8; j++) p[j] = *(const short*)&tile[rb * 8 + j][c];
    *(bf16x8*)(out + (size_t)(c0 + c) * R + r0 + rb * 8) = p;
  }
}

// ---------------- fused embedding gather + LN; writes hs = emb + LN(emb) ------
// R11: residual pre-sum fusion. Downstream (MODE=1 GEMM) needs only
// h + x = emb + LN(emb); write ONE f32 stream instead of two (saves 33.5MB).
__global__ void k_embln(const int* __restrict__ tok, const float* __restrict__ emb,
                        const float* __restrict__ g, const float* __restrict__ b,
                        bf16* __restrict__ ob, float* __restrict__ hs) {
  int row = blockIdx.x;
  int tid = threadIdx.x;
  int t = tok[row];
  float4 v = ((const float4*)(emb + (size_t)t * kD))[tid];
  float sum = v.x + v.y + v.z + v.w;
  float sq = fmaf(v.x, v.x, fmaf(v.y, v.y, fmaf(v.z, v.z, v.w * v.w)));
#pragma unroll
  for (int o = 32; o > 0; o >>= 1) {
    sum += __shfl_down(sum, o);
    sq += __shfl_down(sq, o);
  }
  __shared__ float ss[4], sk[4];
  int w = tid >> 6;
  if ((tid & 63) == 0) { ss[w] = sum; sk[w] = sq; }
  __syncthreads();
  float ts = ss[0] + ss[1] + ss[2] + ss[3];
  float tq = sk[0] + sk[1] + sk[2] + sk[3];
  float mu = ts * (1.0f / kD);
  float var = tq * (1.0f / kD) - mu * mu;
  float rstd = rsqrtf(var + 1e-5f);
  float4 gg = ((const float4*)g)[tid];
  float4 bb = ((const float4*)b)[tid];
  float4 o;
  o.x = fmaf((v.x - mu) * rstd, gg.x, bb.x);
  o.y = fmaf((v.y - mu) * rstd, gg.y, bb.y);
  o.z = fmaf((v.z - mu) * rstd, gg.z, bb.z);
  o.w = fmaf((v.w - mu) * rstd, gg.w, bb.w);
  union { ushort4 u; bf16 hh[4]; } pk;
  pk.hh[0] = __float2bfloat16(o.x);
  pk.hh[1] = __float2bfloat16(o.y);
  pk.hh[2] = __float2bfloat16(o.z);
  pk.hh[3] = __float2bfloat16(o.w);
  *(ushort4*)(ob + (size_t)row * kD + tid * 4) = pk.u;
  float4 hv;
  hv.x = v.x + o.x; hv.y = v.y + o.y; hv.z = v.z + o.z; hv.w = v.w + o.w;
  ((float4*)(hs + (size_t)row * kD))[tid] = hv;
}

// ---------------- row layernorm (D=1024), 256 threads/row ----------------
// WSUM: of = in + LN(in)  (residual pre-sum for the MODE=1 GEMM)
template <bool WSUM>
__global__ void k_ln(const float* __restrict__ in, const float* __restrict__ g,
                     const float* __restrict__ b, bf16* __restrict__ ob,
                     float* __restrict__ of) {
  int row = blockIdx.x;
  int tid = threadIdx.x;
  const float4* x4 = (const float4*)(in + (size_t)row * kD);
  float4 v = x4[tid];
  float sum = v.x + v.y + v.z + v.w;
  float sq = fmaf(v.x, v.x, fmaf(v.y, v.y, fmaf(v.z, v.z, v.w * v.w)));
#pragma unroll
  for (int o = 32; o > 0; o >>= 1) {
    sum += __shfl_down(sum, o);
    sq += __shfl_down(sq, o);
  }
  __shared__ float ss[4], sk[4];
  int w = tid >> 6;
  if ((tid & 63) == 0) { ss[w] = sum; sk[w] = sq; }
  __syncthreads();
  float ts = ss[0] + ss[1] + ss[2] + ss[3];
  float tq = sk[0] + sk[1] + sk[2] + sk[3];
  float mu = ts * (1.0f / kD);
  float var = tq * (1.0f / kD) - mu * mu;
  float rstd = rsqrtf(var + 1e-5f);
  float4 gg = ((const float4*)g)[tid];
  float4 bb = ((const float4*)b)[tid];
  float4 o;
  o.x = fmaf((v.x - mu) * rstd, gg.x, bb.x);
  o.y = fmaf((v.y - mu) * rstd, gg.y, bb.y);
  o.z = fmaf((v.z - mu) * rstd, gg.z, bb.z);
  o.w = fmaf((v.w - mu) * rstd, gg.w, bb.w);
  union { ushort4 u; bf16 h[4]; } pk;
  pk.h[0] = __float2bfloat16(o.x);
  pk.h[1] = __float2bfloat16(o.y);
  pk.h[2] = __float2bfloat16(o.z);
  pk.h[3] = __float2bfloat16(o.w);
  *(ushort4*)(ob + (size_t)row * kD + tid * 4) = pk.u;
  if constexpr (WSUM) {
    float4 hv;
    hv.x = v.x + o.x; hv.y = v.y + o.y; hv.z = v.z + o.z; hv.w = v.w + o.w;
    ((float4*)(of + (size_t)row * kD))[tid] = hv;
  }
}

// ---------------- phasor scan: pass A (chunk partial sums) ----------------
__global__ void k_scan_part(const float* __restrict__ v, const float* __restrict__ c,
                            const float* __restrict__ s, float* __restrict__ pr,
                            float* __restrict__ pi) {
  int tid = blockIdx.x * 256 + threadIdx.x;  // b*16384 + ch*1024 + d
  int d = tid & (kD - 1);
  int ch = (tid >> 10) & (kNC - 1);
  int b = tid >> 14;
  const float* vp = v + ((size_t)b * kL + ch * kCH) * kD + d;
  const float* cp = c + (size_t)(ch * kCH) * kD + d;
  const float* sp = s + (size_t)(ch * kCH) * kD + d;
  float ar = 0.f, ai = 0.f;
  for (int i = 0; i < kCH; i++) {
    float vv = vp[i * kD];
    ar = fmaf(vv, cp[i * kD], ar);
    ai = fmaf(vv, sp[i * kD], ai);
  }
  pr[tid] = ar;
  pi[tid] = ai;
}

// ---------------- phasor scan: pass B (apply, in-place over v) ----------------
__global__ void k_scan_apply(float* __restrict__ v, const float* __restrict__ c,
                             const float* __restrict__ s, const float* __restrict__ pr,
                             const float* __restrict__ pi) {
  int tid = blockIdx.x * 256 + threadIdx.x;
  int d = tid & (kD - 1);
  int ch = (tid >> 10) & (kNC - 1);
  int b = tid >> 14;
  float ar = 0.f, ai = 0.f;
  int pbase = (b << 14) + d;
  for (int cc = 0; cc < ch; cc++) {
    ar += pr[pbase + cc * kD];
    ai += pi[pbase + cc * kD];
  }
  float* vp = v + ((size_t)b * kL + ch * kCH) * kD + d;
  const float* cp = c + (size_t)(ch * kCH) * kD + d;
  const float* sp = s + (size_t)(ch * kCH) * kD + d;
  for (int i = 0; i < kCH; i++) {
    float vv = vp[i * kD];
    float cv = cp[i * kD], sv = sp[i * kD];
    ar = fmaf(vv, cv, ar);
    ai = fmaf(vv, sv, ai);
    vp[i * kD] = (ar * cv + ai * sv) * 0.03125f;  // 1/sqrt(1024)
  }
}

// ============================================================================
// 128x256-tile D x D GEMM — R10-proven port of the head template (2 phases;
// A consumed in ph0). XOR-swizzled LDS, counted vmcnt, setprio, XCD map.
// R11: MODE=1 reads a SINGLE residual stream hs = in + LN(in) (pre-summed by
// the producer) instead of two f32 streams (-33.5MB/dispatch).
// ============================================================================
template <int MODE>
__global__ __launch_bounds__(512, 2) void k_gemm_bt2(
    const bf16* __restrict__ A, const bf16* __restrict__ BT,
    const float* __restrict__ bias, const float* __restrict__ hres,
    float* __restrict__ Cout, int Md, int Nd, int Kd) {
  __shared__ __align__(16) bf16 As[2][8192];   // [buf][128 rows x 64 k]
  __shared__ __align__(16) bf16 Bs[2][16384];  // [buf][256 rows x 64 k]

  int gx = gridDim.x;                 // 64
  int wg = blockIdx.y * gx + blockIdx.x;
  int mch = gx >> 3;                  // 8
  int xcd = wg & 7;
  int r = wg >> 3;
  int bm = xcd * mch + (r % mch);
  int bn = r / mch;
  int m0 = bm * 128, n0 = bn * 256;

  int tid = threadIdx.x;
  int wid = tid >> 6, lane = tid & 63;
  int wr = wid >> 2, wc = wid & 3;    // wave tile: 64 rows (wr) x 64 cols (wc)

  size_t KdS = (size_t)Kd;
  int srow = tid >> 3;                               // 0..63
  int sk = (((tid & 7) ^ (srow & 7)) << 3);
  const bf16* aSrc = A + (size_t)(m0 + srow) * KdS + sk;
  const bf16* bSrc = BT + (size_t)(n0 + srow) * KdS + sk;
  int ldst = wid * 512;

#define STAGE_A2(buf, t)                                                                \
  do {                                                                                  \
    __builtin_amdgcn_global_load_lds(GPTR(aSrc + (size_t)(t) * 64),                     \
                                     LPTR(&As[buf][ldst]), 16, 0, 0);                   \
    __builtin_amdgcn_global_load_lds(GPTR(aSrc + (size_t)64 * KdS + (size_t)(t) * 64),  \
                                     LPTR(&As[buf][4096 + ldst]), 16, 0, 0);            \
  } while (0)
#define STAGE_B2(buf, h, t)                                                             \
  do {                                                                                  \
    __builtin_amdgcn_global_load_lds(GPTR(bSrc + (size_t)((h) * 128) * KdS + (t) * 64), \
                                     LPTR(&Bs[buf][(h) * 8192 + ldst]), 16, 0, 0);      \
    __builtin_amdgcn_global_load_lds(                                                   \
        GPTR(bSrc + (size_t)((h) * 128 + 64) * KdS + (t) * 64),                         \
        LPTR(&Bs[buf][(h) * 8192 + 4096 + ldst]), 16, 0, 0);                            \
  } while (0)

  int frow = lane & 15;
  int khi = lane >> 4;
  int rx = frow & 7;
  int lk0 = ((khi) ^ rx) << 3;        // k 0..31 (after source swizzle)
  int lk1 = ((4 + khi) ^ rx) << 3;    // k 32..63
  int wr16 = wr * 16;
  int wc64 = wc * 64;

  f32x4 acc[4][4];
#pragma unroll
  for (int i = 0; i < 4; i++)
#pragma unroll
    for (int j = 0; j < 4; j++) acc[i][j] = (f32x4){0.f, 0.f, 0.f, 0.f};

  const int NT = Kd >> 6;  // 16

  // ---- prologue: A(0),B(0) -> buf0; A(1) -> buf1; wait all but A(1)
  STAGE_A2(0, 0);
  STAGE_B2(0, 0, 0);
  STAGE_B2(0, 1, 0);
  STAGE_A2(1, 1);
  asm volatile("s_waitcnt vmcnt(2)" ::: "memory");
  __builtin_amdgcn_s_barrier();
  __builtin_amdgcn_sched_barrier(0);

  for (int t = 0; t < NT; ++t) {
    int c = t & 1, o = c ^ 1;
    const bf16* Ac = As[c];
    const bf16* Bc = Bs[c];
    bf16x8 a[4][2], b[2][2], b2[2][2];

    // ===== phase 0: read all a + b(n0..1); stage B(t+1)->o; MFMA m0..3 x n0..1
#pragma unroll
    for (int m = 0; m < 4; m++) {
      int ro = (m * 32 + wr16 + frow) * 64;
      a[m][0] = *(const bf16x8*)(Ac + ro + lk0);
      a[m][1] = *(const bf16x8*)(Ac + ro + lk1);
    }
#pragma unroll
    for (int n = 0; n < 2; n++) {
      int ro = (wc64 + n * 16 + frow) * 64;
      b[n][0] = *(const bf16x8*)(Bc + ro + lk0);
      b[n][1] = *(const bf16x8*)(Bc + ro + lk1);
    }
    if (t + 1 < NT) {
      STAGE_B2(o, 0, t + 1);
      STAGE_B2(o, 1, t + 1);
    }
    __builtin_amdgcn_s_barrier();
    asm volatile("s_waitcnt lgkmcnt(0)" ::: "memory");
    __builtin_amdgcn_sched_barrier(0);
    __builtin_amdgcn_s_setprio(1);
#pragma unroll
    for (int m = 0; m < 4; m++)
#pragma unroll
      for (int n = 0; n < 2; n++) {
        acc[m][n] = __builtin_amdgcn_mfma_f32_16x16x32_bf16(a[m][0], b[n][0], acc[m][n], 0, 0, 0);
        acc[m][n] = __builtin_amdgcn_mfma_f32_16x16x32_bf16(a[m][1], b[n][1], acc[m][n], 0, 0, 0);
      }
    __builtin_amdgcn_s_setprio(0);
    __builtin_amdgcn_s_barrier();
    __builtin_amdgcn_sched_barrier(0);

    // ===== phase 1: read b2(n2..3); stage A(t+2)->c; MFMA m0..3 x n2..3; gate
#pragma unroll
    for (int n = 0; n < 2; n++) {
      int ro = (wc64 + (n + 2) * 16 + frow) * 64;
      b2[n][0] = *(const bf16x8*)(Bc + ro + lk0);
      b2[n][1] = *(const bf16x8*)(Bc + ro + lk1);
    }
    if (t + 2 < NT) STAGE_A2(c, t + 2);
    __builtin_amdgcn_s_barrier();
    asm volatile("s_waitcnt lgkmcnt(0)" ::: "memory");
    __builtin_amdgcn_sched_barrier(0);
    __builtin_amdgcn_s_setprio(1);
#pragma unroll
    for (int m = 0; m < 4; m++)
#pragma unroll
      for (int n = 0; n < 2; n++) {
        acc[m][n + 2] = __builtin_amdgcn_mfma_f32_16x16x32_bf16(a[m][0], b2[n][0], acc[m][n + 2], 0, 0, 0);
        acc[m][n + 2] = __builtin_amdgcn_mfma_f32_16x16x32_bf16(a[m][1], b2[n][1], acc[m][n + 2], 0, 0, 0);
      }
    __builtin_amdgcn_s_setprio(0);
    if (t < NT - 2) {
      asm volatile("s_waitcnt vmcnt(2)" ::: "memory");  // only A(t+2) in flight
    } else if (t == NT - 2) {
      asm volatile("s_waitcnt vmcnt(0)" ::: "memory");  // drain for last tile
    }
    __builtin_amdgcn_s_barrier();
    __builtin_amdgcn_sched_barrier(0);
  }
#undef STAGE_A2
#undef STAGE_B2

  // ---- epilogue: plain stores (outputs re-read by later kernels) ----
  int cr = (lane >> 4) * 4;
  int ccl = lane & 15;
#pragma unroll
  for (int m = 0; m < 4; m++) {
#pragma unroll
    for (int n = 0; n < 4; n++) {
      int col = n0 + wc64 + n * 16 + ccl;
      float bv = bias[col];
#pragma unroll
      for (int r2 = 0; r2 < 4; r2++) {
        int row = m0 + m * 32 + wr16 + cr + r2;
        size_t idx = (size_t)row * Nd + col;
        float val = acc[m][n][r2] + bv;
        if (MODE == 1) val += hres[idx];
        Cout[idx] = val;
      }
    }
  }
}

// ============================================================================
// 256x256 4-phase/K-tile head GEMM (R9-proven: ~690 us / 777 TF).
// wc64 contiguous-col waves; full-line nt epilogue via per-wave LDS
// transpose (WRITE confirmed 1.03e6; nt preserves L3 for the next graph
// iteration: total-head = 271-277 us vs 334-354 with plain stores).
// DO NOT MODIFY without within-session A/B.
// ============================================================================
__global__ __launch_bounds__(512, 2) void k_gemm256p8(
    const bf16* __restrict__ A, const bf16* __restrict__ BT,
    const float* __restrict__ bias, float* __restrict__ Cout,
    int Md, int Nd, int Kd) {
  __shared__ __align__(16) bf16 As[2][16384];  // [buf][256 rows x 64 k]
  __shared__ __align__(16) bf16 Bs[2][16384];

  int gx = gridDim.x;
  int wg = blockIdx.y * gx + blockIdx.x;
  int mch = gx >> 3;                 // bm-chunk per XCD (gx % 8 == 0)
  int xcd = wg & 7;
  int r = wg >> 3;
  int bm = xcd * mch + (r % mch);
  int bn = r / mch;
  int m0 = bm * 256, n0 = bn * 256;

  int tid = threadIdx.x;
  int wid = tid >> 6, lane = tid & 63;
  int wr = wid >> 2, wc = wid & 3;  // A row m*32+wr*16; B col block wc*64 (contiguous)

  size_t KdS = (size_t)Kd;
  int srow = tid >> 3;                               // 0..63 slab row
  int sk = (((tid & 7) ^ (srow & 7)) << 3);          // source elem offset
  const bf16* aSrc = A + (size_t)(m0 + srow) * KdS + sk;
  const bf16* bSrc = BT + (size_t)(n0 + srow) * KdS + sk;
  int ldst = wid * 512;                              // wave-uniform elem base

#define STAGE_A(buf, h, t)                                                              \
  do {                                                                                  \
    __builtin_amdgcn_global_load_lds(GPTR(aSrc + (size_t)((h) * 128) * KdS + (t) * 64), \
                                     LPTR(&As[buf][(h) * 8192 + ldst]), 16, 0, 0);      \
    __builtin_amdgcn_global_load_lds(                                                   \
        GPTR(aSrc + (size_t)((h) * 128 + 64) * KdS + (t) * 64),                         \
        LPTR(&As[buf][(h) * 8192 + 4096 + ldst]), 16, 0, 0);                            \
  } while (0)
#define STAGE_B(buf, h, t)                                                              \
  do {                                                                                  \
    __builtin_amdgcn_global_load_lds(GPTR(bSrc + (size_t)((h) * 128) * KdS + (t) * 64), \
                                     LPTR(&Bs[buf][(h) * 8192 + ldst]), 16, 0, 0);      \
    __builtin_amdgcn_global_load_lds(                                                   \
        GPTR(bSrc + (size_t)((h) * 128 + 64) * KdS + (t) * 64),                         \
        LPTR(&Bs[buf][(h) * 8192 + 4096 + ldst]), 16, 0, 0);                            \
  } while (0)

  int frow = lane & 15;
  int khi = lane >> 4;   // 0..3
  int rx = frow & 7;
  int lk0 = ((khi) ^ rx) << 3;        // k-window 0 (k 0..31)
  int lk1 = ((4 + khi) ^ rx) << 3;    // k-window 1 (k 32..63)
  int wr16 = wr * 16;
  int wc64 = wc * 64;                 // contiguous 64-col block per wave

  f32x4 acc[8][4];
#pragma unroll
  for (int m = 0; m < 8; m++)
#pragma unroll
    for (int n = 0; n < 4; n++) acc[m][n] = (f32x4){0.f, 0.f, 0.f, 0.f};

  const int NT = Kd >> 6;  // 16 K-tiles of 64

  // ---- prologue: tile0 fully -> buf0 (A0,B0,B1,A1), tile1 A0,B0,B1 -> buf1
  STAGE_A(0, 0, 0);
  STAGE_B(0, 0, 0);
  STAGE_B(0, 1, 0);
  STAGE_A(0, 1, 0);
  STAGE_A(1, 0, 1);
  STAGE_B(1, 0, 1);
  STAGE_B(1, 1, 1);
  asm volatile("s_waitcnt vmcnt(6)" ::: "memory");  // tile0's 8 loads landed
  __builtin_amdgcn_s_barrier();
  __builtin_amdgcn_sched_barrier(0);

  for (int t = 0; t < NT; ++t) {
    int c = t & 1, o = c ^ 1;
    const bf16* Ac = As[c];
    const bf16* Bc = Bs[c];
    bf16x8 a[4][2], b[2][2], b2[2][2];

    // ===== phase 0: read a(m0..3) + b(n0..1); stage A-h1(t+1)->oth; MFMA
#pragma unroll
    for (int m = 0; m < 4; m++) {
      int ro = (m * 32 + wr16 + frow) * 64;
      a[m][0] = *(const bf16x8*)(Ac + ro + lk0);
      a[m][1] = *(const bf16x8*)(Ac + ro + lk1);
    }
#pragma unroll
    for (int n = 0; n < 2; n++) {
      int ro = (wc64 + n * 16 + frow) * 64;
      b[n][0] = *(const bf16x8*)(Bc + ro + lk0);
      b[n][1] = *(const bf16x8*)(Bc + ro + lk1);
    }
    if (t + 1 < NT) STAGE_A(o, 1, t + 1);
    __builtin_amdgcn_s_barrier();
    asm volatile("s_waitcnt lgkmcnt(0)" ::: "memory");
    __builtin_amdgcn_sched_barrier(0);
    __builtin_amdgcn_s_setprio(1);
#pragma unroll
    for (int m = 0; m < 4; m++)
#pragma unroll
      for (int n = 0; n < 2; n++) {
        acc[m][n] = __builtin_amdgcn_mfma_f32_16x16x32_bf16(a[m][0], b[n][0], acc[m][n], 0, 0, 0);
        acc[m][n] = __builtin_amdgcn_mfma_f32_16x16x32_bf16(a[m][1], b[n][1], acc[m][n], 0, 0, 0);
      }
    __builtin_amdgcn_s_setprio(0);
    __builtin_amdgcn_s_barrier();
    __builtin_amdgcn_sched_barrier(0);

    // ===== phase 1: read b2(n2..3); stage A-h0(t+2)->cur; MFMA
#pragma unroll
    for (int n = 0; n < 2; n++) {
      int ro = (wc64 + (n + 2) * 16 + frow) * 64;
      b2[n][0] = *(const bf16x8*)(Bc + ro + lk0);
      b2[n][1] = *(const bf16x8*)(Bc + ro + lk1);
    }
    if (t + 2 < NT) STAGE_A(c, 0, t + 2);
    __builtin_amdgcn_s_barrier();
    asm volatile("s_waitcnt lgkmcnt(0)" ::: "memory");
    __builtin_amdgcn_sched_barrier(0);
    __builtin_amdgcn_s_setprio(1);
#pragma unroll
    for (int m = 0; m < 4; m++)
#pragma unroll
      for (int n = 0; n < 2; n++) {
        acc[m][n + 2] = __builtin_amdgcn_mfma_f32_16x16x32_bf16(a[m][0], b2[n][0], acc[m][n + 2], 0, 0, 0);
        acc[m][n + 2] = __builtin_amdgcn_mfma_f32_16x16x32_bf16(a[m][1], b2[n][1], acc[m][n + 2], 0, 0, 0);
      }
    __builtin_amdgcn_s_setprio(0);
    __builtin_amdgcn_s_barrier();
    __builtin_amdgcn_sched_barrier(0);

    // ===== phase 2: read a(m4..7); stage B-h0(t+2)->cur; MFMA
#pragma unroll
    for (int m = 0; m < 4; m++) {
      int ro = ((m + 4) * 32 + wr16 + frow) * 64;
      a[m][0] = *(const bf16x8*)(Ac + ro + lk0);
      a[m][1] = *(const bf16x8*)(Ac + ro + lk1);
    }
    if (t + 2 < NT) STAGE_B(c, 0, t + 2);
    __builtin_amdgcn_s_barrier();
    asm volatile("s_waitcnt lgkmcnt(0)" ::: "memory");
    __builtin_amdgcn_sched_barrier(0);
    __builtin_amdgcn_s_setprio(1);
#pragma unroll
    for (int m = 0; m < 4; m++)
#pragma unroll
      for (int n = 0; n < 2; n++) {
        acc[m + 4][n] = __builtin_amdgcn_mfma_f32_16x16x32_bf16(a[m][0], b[n][0], acc[m + 4][n], 0, 0, 0);
        acc[m + 4][n] = __builtin_amdgcn_mfma_f32_16x16x32_bf16(a[m][1], b[n][1], acc[m + 4][n], 0, 0, 0);
      }
    __builtin_amdgcn_s_setprio(0);
    __builtin_amdgcn_s_barrier();
    __builtin_amdgcn_sched_barrier(0);

    // ===== phase 3: no reads; stage B-h1(t+2)->cur; MFMA; gate
    if (t + 2 < NT) STAGE_B(c, 1, t + 2);
    __builtin_amdgcn_s_barrier();
    __builtin_amdgcn_sched_barrier(0);
    __builtin_amdgcn_s_setprio(1);
#pragma unroll
    for (int m = 0; m < 4; m++)
#pragma unroll
      for (int n = 0; n < 2; n++) {
        acc[m + 4][n + 2] = __builtin_amdgcn_mfma_f32_16x16x32_bf16(a[m][0], b2[n][0], acc[m + 4][n + 2], 0, 0, 0);
        acc[m + 4][n + 2] = __builtin_amdgcn_mfma_f32_16x16x32_bf16(a[m][1], b2[n][1], acc[m + 4][n + 2], 0, 0, 0);
      }
    __builtin_amdgcn_s_setprio(0);
    if (t < NT - 2) {
      asm volatile("s_waitcnt vmcnt(6)" ::: "memory");  // 3 half-tiles in flight
    } else if (t == NT - 2) {
      asm volatile("s_waitcnt vmcnt(0)" ::: "memory");  // drain for last tile
    }
    __builtin_amdgcn_s_barrier();
    __builtin_amdgcn_sched_barrier(0);
  }
#undef STAGE_A
#undef STAGE_B

  // ---- epilogue: per-wave LDS transpose -> full-line nt dwordx4 stores ----
  float* eplds = (float*)&As[0][0] + wid * 1088;  // 1088 f32 = 4352 B per wave
  int q = lane & 15;
  int g = lane >> 4;
  float bv[4];
#pragma unroll
  for (int n = 0; n < 4; n++) bv[n] = bias[n0 + wc64 + n * 16 + q];
#pragma unroll
  for (int m = 0; m < 8; m++) {
#pragma unroll
    for (int n = 0; n < 4; n++)
#pragma unroll
      for (int r2 = 0; r2 < 4; r2++)
        eplds[(g * 4 + r2) * 68 + n * 16 + q] = acc[m][n][r2] + bv[n];
    asm volatile("s_waitcnt lgkmcnt(0)" ::: "memory");
    __builtin_amdgcn_sched_barrier(0);
#pragma unroll
    for (int rr = 0; rr < 4; rr++) {
      f32x4 v4 = *(const f32x4*)(eplds + (rr * 4 + g) * 68 + q * 4);
      int row = m0 + m * 32 + wr16 + rr * 4 + g;
      __builtin_nontemporal_store(
          v4, (f32x4*)(Cout + (size_t)row * Nd + n0 + wc64 + q * 4));
    }
    asm volatile("s_waitcnt lgkmcnt(0)" ::: "memory");  // reads done before next m overwrites
    __builtin_amdgcn_sched_barrier(0);
  }
}

extern "C" void kernel_launch(void* const* d_in, const int* in_sizes, int n_in,
                              void* d_out, int out_size, void* d_ws, size_t ws_size,
                              hipStream_t stream) {
  const int* tokens   = (const int*)d_in[0];
  const float* embed  = (const float*)d_in[1];
  const float* ln1_g  = (const float*)d_in[2];
  const float* ln1_b  = (const float*)d_in[3];
  const float* ph1    = (const float*)d_in[4];
  const float* wv1    = (const float*)d_in[5];
  const float* bv1    = (const float*)d_in[6];
  const float* lno1_g = (const float*)d_in[7];
  const float* lno1_b = (const float*)d_in[8];
  const float* wo1    = (const float*)d_in[9];
  const float* bo1    = (const float*)d_in[10];
  const float* ln2_g  = (const float*)d_in[11];
  const float* ln2_b  = (const float*)d_in[12];
  const float* ph2    = (const float*)d_in[13];
  const float* wv2    = (const float*)d_in[14];
  const float* bv2    = (const float*)d_in[15];
  const float* lno2_g = (const float*)d_in[16];
  const float* lno2_b = (const float*)d_in[17];
  const float* wo2    = (const float*)d_in[18];
  const float* bo2    = (const float*)d_in[19];
  const float* ln3_g  = (const float*)d_in[20];
  const float* ln3_b  = (const float*)d_in[21];
  const float* w_head = (const float*)d_in[22];
  const float* b_head = (const float*)d_in[23];

  float* out = (float*)d_out;

  // ws: bf16 weights (transposed) + bf16 LN output  (~91 MB)
  char* ws = (char*)d_ws;
  bf16* whT  = (bf16*)ws;                    // [V][D]
  bf16* wv1T = whT + (size_t)kV * kD;        // [D][D] each
  bf16* wo1T = wv1T + (size_t)kD * kD;
  bf16* wv2T = wo1T + (size_t)kD * kD;
  bf16* wo2T = wv2T + (size_t)kD * kD;
  bf16* xb   = wo2T + (size_t)kD * kD;       // [M][D] bf16 (LN output, reused)

  // f32 activations live in d_out (1 GB); fully overwritten by the final GEMM
  float* h  = out;                            // [M][D] residual stream
  float* hs = h + (size_t)kM * kD;            // [M][D] in + LN(in) (pre-summed residual)
  float* vb = hs + (size_t)kM * kD;           // [M][D] v / retrieved (in-place)
  float* ct = vb + (size_t)kM * kD;           // [L][D]
  float* st = ct + (size_t)kL * kD;           // [L][D]
  float* pr = st + (size_t)kL * kD;           // [B][NC][D]
  float* pi = pr + (size_t)kB * kNC * kD;

  // weight conversion (transpose to [N][K] bf16), 64x64 vectorized tiles
  k_tcvt64<<<dim3(kD / 64, kD / 64), 256, 0, stream>>>(wv1, wv1T, kD, kD);
  k_tcvt64<<<dim3(kD / 64, kD / 64), 256, 0, stream>>>(wo1, wo1T, kD, kD);
  k_tcvt64<<<dim3(kD / 64, kD / 64), 256, 0, stream>>>(wv2, wv2T, kD, kD);
  k_tcvt64<<<dim3(kD / 64, kD / 64), 256, 0, stream>>>(wo2, wo2T, kD, kD);
  k_tcvt64<<<dim3(kV / 64, kD / 64), 256, 0, stream>>>(w_head, whT, kD, kV);

  const int scanBlocks = kB * kNC * kD / 256;  // 256

  // ---- phasor block 1 ----
  k_sincos<<<(kL * kD + 255) / 256, 256, 0, stream>>>(ph1, ct, st, kL * kD);
  k_embln<<<kM, 256, 0, stream>>>(tokens, embed, ln1_g, ln1_b, xb, hs);
  k_gemm_bt2<0><<<dim3(kM / 128, kD / 256), 512, 0, stream>>>(xb, wv1T, bv1, nullptr,
                                                              vb, kM, kD, kD);
  k_scan_part<<<scanBlocks, 256, 0, stream>>>(vb, ct, st, pr, pi);
  k_scan_apply<<<scanBlocks, 256, 0, stream>>>(vb, ct, st, pr, pi);
  k_ln<false><<<kM, 256, 0, stream>>>(vb, lno1_g, lno1_b, xb, nullptr);
  k_gemm_bt2<1><<<dim3(kM / 128, kD / 256), 512, 0, stream>>>(xb, wo1T, bo1, hs,
                                                              h, kM, kD, kD);

  // ---- phasor block 2 ----
  k_sincos<<<(kL * kD + 255) / 256, 256, 0, stream>>>(ph2, ct, st, kL * kD);
  k_ln<true><<<kM, 256, 0, stream>>>(h, ln2_g, ln2_b, xb, hs);
  k_gemm_bt2<0><<<dim3(kM / 128, kD / 256), 512, 0, stream>>>(xb, wv2T, bv2, nullptr,
                                                              vb, kM, kD, kD);
  k_scan_part<<<scanBlocks, 256, 0, stream>>>(vb, ct, st, pr, pi);
  k_scan_apply<<<scanBlocks, 256, 0, stream>>>(vb, ct, st, pr, pi);
  k_ln<false><<<kM, 256, 0, stream>>>(vb, lno2_g, lno2_b, xb, nullptr);
  k_gemm_bt2<1><<<dim3(kM / 128, kD / 256), 512, 0, stream>>>(xb, wo2T, bo2, hs,
                                                              h, kM, kD, kD);

  // ---- final LN + head GEMM (R9-proven: 4-phase + full-line nt epilogue) ----
  k_ln<false><<<kM, 256, 0, stream>>>(h, ln3_g, ln3_b, xb, nullptr);
  k_gemm256p8<<<dim3(kM / 256, kV / 256), 512, 0, stream>>>(xb, whT, b_head, out,
                                                            kM, kV, kD);
}